// Round 2
// 459.288 us; speedup vs baseline: 1.2924x; 1.2924x over previous
//
#include <hip/hip_runtime.h>
#include <hip/hip_bf16.h>
#include <cstdint>

#define NEG (-1.0e30f)
#define INVLN2 1.44269504088896340736f
#define LN2    0.69314718055994530942f

typedef unsigned short u16;
typedef __attribute__((ext_vector_type(8))) short short8;
typedef __attribute__((ext_vector_type(4))) float f32x4;

typedef const __attribute__((address_space(1))) void cg_void;
typedef __attribute__((address_space(3))) void lds_void;

// dims
#define Bsz   32
#define Tlen  1000
#define Cdim  512
#define Vdim  2000
#define Udim  100
#define Mrows (Bsz * Tlen)   // 32000
#define Npad  2048
#define GROW  256            // G row stride in floats (1024 B): lane i owns
                             // float4 {p(tgt[2i]), p(tgt[2i+1]), p(blank), 0} (LINEAR probs)

// ws layout (bytes). G (32.768 MB) aliases a_bf exactly (dead after gemm).
#define WS_ABF 0u
#define WS_G   0u
#define WS_WBF 32768000u                    // a_bf/G: 32000*1024
#define WS_Z   (WS_WBF + 2097152u)          // w_bf: 2048*512*2
#define WS_ACC (WS_Z + 128000000u)          // Z: 32000*2000*2; then accum: 2 floats

__device__ inline u16 f2bf(float x) {
  uint32_t u = __float_as_uint(x);
  uint32_t r = (u + 0x7fffu + ((u >> 16) & 1u)) >> 16;
  return (u16)r;
}
__device__ inline float bf2f(u16 u) {
  return __uint_as_float(((uint32_t)u) << 16);
}

__device__ inline float waveMax(float v) {
  #pragma unroll
  for (int o = 32; o > 0; o >>= 1) v = fmaxf(v, __shfl_down(v, o));
  return v;
}
__device__ inline float waveSum(float v) {
  #pragma unroll
  for (int o = 32; o > 0; o >>= 1) v += __shfl_down(v, o);
  return v;
}

// shift value from lane-1 into this lane via DPP wave_shr:1 (VALU, no LDS).
__device__ inline float shiftup1(float x, float fill) {
  int r = __builtin_amdgcn_update_dpp(__float_as_int(fill), __float_as_int(x),
                                      0x138, 0xF, 0xF, false);
  return __int_as_float(r);
}

// ---------------- K1: fp32 -> bf16 conversion, vectorized ------------------
__global__ void convert_kernel(const float4* __restrict__ enc4, const float4* __restrict__ W4,
                               uint4* __restrict__ a4, uint4* __restrict__ w4,
                               float* __restrict__ accum) {
  int idx = blockIdx.x * blockDim.x + threadIdx.x;
  int stride = gridDim.x * blockDim.x;
  if (idx == 0) { accum[0] = 0.0f; accum[1] = 0.0f; }
  const int nA = Mrows * Cdim / 8;
  const int nW = Vdim * Cdim / 8;
  const int nWp = Npad * Cdim / 8;
  for (int i = idx; i < nA; i += stride) {
    float4 x = enc4[2 * i], y = enc4[2 * i + 1];
    uint4 o;
    o.x = (uint32_t)f2bf(x.x) | ((uint32_t)f2bf(x.y) << 16);
    o.y = (uint32_t)f2bf(x.z) | ((uint32_t)f2bf(x.w) << 16);
    o.z = (uint32_t)f2bf(y.x) | ((uint32_t)f2bf(y.y) << 16);
    o.w = (uint32_t)f2bf(y.z) | ((uint32_t)f2bf(y.w) << 16);
    a4[i] = o;
  }
  for (int i = idx; i < nWp; i += stride) {
    uint4 o = {0, 0, 0, 0};
    if (i < nW) {
      float4 x = W4[2 * i], y = W4[2 * i + 1];
      o.x = (uint32_t)f2bf(x.x) | ((uint32_t)f2bf(x.y) << 16);
      o.y = (uint32_t)f2bf(x.z) | ((uint32_t)f2bf(x.w) << 16);
      o.z = (uint32_t)f2bf(y.x) | ((uint32_t)f2bf(y.y) << 16);
      o.w = (uint32_t)f2bf(y.z) | ((uint32_t)f2bf(y.w) << 16);
    }
    w4[i] = o;
  }
}

// ---------------- K2: bf16 GEMM (A: 32000x512, W: 2048x512, C = A*W^T) -----
__global__ __launch_bounds__(256) void gemm_kernel(const u16* __restrict__ A,
                                                   const u16* __restrict__ Wb,
                                                   u16* __restrict__ Z) {
  __shared__ __attribute__((aligned(16))) u16 As[128 * 64];
  __shared__ __attribute__((aligned(16))) u16 Bs[128 * 64];
  const int tid = threadIdx.x;
  const int wave = tid >> 6;
  const int lane = tid & 63;
  const int nBase = blockIdx.x * 128;
  const int mBase = blockIdx.y * 128;
  const int m_lane = lane & 15;
  const int quad = lane >> 4;

  f32x4 acc[4][4];
  const f32x4 zero4 = {0.0f, 0.0f, 0.0f, 0.0f};
  #pragma unroll
  for (int i = 0; i < 4; ++i)
    #pragma unroll
    for (int j = 0; j < 4; ++j) acc[i][j] = zero4;

  for (int k0 = 0; k0 < Cdim; k0 += 64) {
    #pragma unroll
    for (int r = 0; r < 4; ++r) {
      int u = r * 256 + tid;
      int g = u >> 3;
      int q = (u & 7) ^ (g & 7);
      const u16* gpA = A + ((size_t)(mBase + g) << 9) + (k0 + (q << 3));
      __builtin_amdgcn_global_load_lds((cg_void*)gpA, (lds_void*)&As[(r * 4 + wave) * 512],
                                       16, 0, 0);
      const u16* gpB = Wb + ((size_t)(nBase + g) << 9) + (k0 + (q << 3));
      __builtin_amdgcn_global_load_lds((cg_void*)gpB, (lds_void*)&Bs[(r * 4 + wave) * 512],
                                       16, 0, 0);
    }
    __syncthreads();
    #pragma unroll
    for (int kk = 0; kk < 2; ++kk) {
      short8 af[4], bfv[4];
      #pragma unroll
      for (int mi = 0; mi < 4; ++mi) {
        int row = (wave >> 1) * 64 + mi * 16 + m_lane;
        int q = (kk * 4 + quad) ^ (row & 7);
        af[mi] = *(const short8*)&As[row * 64 + (q << 3)];
      }
      #pragma unroll
      for (int ni = 0; ni < 4; ++ni) {
        int col = (wave & 1) * 64 + ni * 16 + m_lane;
        int q = (kk * 4 + quad) ^ (col & 7);
        bfv[ni] = *(const short8*)&Bs[col * 64 + (q << 3)];
      }
      #pragma unroll
      for (int mi = 0; mi < 4; ++mi)
        #pragma unroll
        for (int ni = 0; ni < 4; ++ni)
          acc[mi][ni] = __builtin_amdgcn_mfma_f32_16x16x32_bf16(af[mi], bfv[ni],
                                                                acc[mi][ni], 0, 0, 0);
    }
    __syncthreads();
  }
  #pragma unroll
  for (int ni = 0; ni < 4; ++ni) {
    int col = nBase + (wave & 1) * 64 + ni * 16 + m_lane;
    if (col < Vdim) {
      #pragma unroll
      for (int mi = 0; mi < 4; ++mi) {
        int row0 = mBase + (wave >> 1) * 64 + mi * 16 + quad * 4;
        #pragma unroll
        for (int rg = 0; rg < 4; ++rg)
          Z[(size_t)(row0 + rg) * Vdim + col] = f2bf(acc[mi][ni][rg]);
      }
    }
  }
}

// ---------------- K3: fused softmax stats + CR loss + CTC gather -----------
// Emits G rows of 64 float4s: lane i gets LINEAR probabilities
// {p(tgt[2i]), p(tgt[2i+1]), p(blank), 0}. Label slots with label index
// u >= target_length are zeroed: this keeps the entire s > 2*tl state region
// of the CTC lattice exactly 0 (those states' multipliers are 0 every step),
// so they can never dominate the wave max in the scan (round-1 inf mode #1).
__global__ __launch_bounds__(256) void cr_stats_kernel(const u16* __restrict__ Z,
                                                       const float* __restrict__ bias,
                                                       const int* __restrict__ lens,
                                                       const int* __restrict__ targets,
                                                       const int* __restrict__ tlens,
                                                       float* __restrict__ G,
                                                       float* __restrict__ accum) {
  int bp = blockIdx.x;   // 0..15
  int t = blockIdx.y;    // 0..999
  int tid = threadIdx.x;
  int wave = tid >> 6, lane = tid & 63;
  size_t r1 = (size_t)bp * Tlen + t;
  size_t r2 = r1 + (size_t)16 * Tlen;
  const u16* z1 = Z + r1 * Vdim;
  const u16* z2 = Z + r2 * Vdim;

  __shared__ float ls1[Vdim];
  __shared__ float ls2[Vdim];
  __shared__ float red[8];

  float v1[8], v2[8];
  float mx1 = NEG, mx2 = NEG;
  #pragma unroll
  for (int i = 0; i < 8; ++i) {
    int col = i * 256 + tid;
    if (col < Vdim) {
      float bb = bias[col];
      v1[i] = bf2f(z1[col]) + bb;
      v2[i] = bf2f(z2[col]) + bb;
      ls1[col] = v1[i];
      ls2[col] = v2[i];
      mx1 = fmaxf(mx1, v1[i]);
      mx2 = fmaxf(mx2, v2[i]);
    } else { v1[i] = NEG; v2[i] = NEG; }
  }
  float w1 = waveMax(mx1), w2 = waveMax(mx2);
  if (lane == 0) { red[wave] = w1; red[4 + wave] = w2; }
  __syncthreads();
  float M1 = fmaxf(fmaxf(red[0], red[1]), fmaxf(red[2], red[3]));
  float M2 = fmaxf(fmaxf(red[4], red[5]), fmaxf(red[6], red[7]));
  __syncthreads();
  float s1 = 0.0f, s2 = 0.0f;
  #pragma unroll
  for (int i = 0; i < 8; ++i) {
    s1 += expf(v1[i] - M1);
    s2 += expf(v2[i] - M2);
  }
  s1 = waveSum(s1); s2 = waveSum(s2);
  if (lane == 0) { red[wave] = s1; red[4 + wave] = s2; }
  __syncthreads();
  float c1 = M1 + logf(red[0] + red[1] + red[2] + red[3]);
  float c2 = M2 + logf(red[4] + red[5] + red[6] + red[7]);

  if (tid < 64) {
    int i1 = min(2 * tid, Udim - 1);
    int i3 = min(2 * tid + 1, Udim - 1);
    int t1a = targets[bp * Udim + i1];
    int t1b = targets[bp * Udim + i3];
    int t2a = targets[(bp + 16) * Udim + i1];
    int t2b = targets[(bp + 16) * Udim + i3];
    int tl1 = tlens[bp];
    int tl2 = tlens[bp + 16];
    // LINEAR probabilities; labels past this sequence's target length -> 0.
    float4 g1 = {(2 * tid < tl1) ? expf(ls1[t1a] - c1) : 0.0f,
                 (2 * tid + 1 < tl1) ? expf(ls1[t1b] - c1) : 0.0f,
                 expf(ls1[0] - c1), 0.0f};
    float4 g2 = {(2 * tid < tl2) ? expf(ls2[t2a] - c2) : 0.0f,
                 (2 * tid + 1 < tl2) ? expf(ls2[t2b] - c2) : 0.0f,
                 expf(ls2[0] - c2), 0.0f};
    *(float4*)(G + r1 * GROW + 4 * tid) = g1;
    *(float4*)(G + r2 * GROW + 4 * tid) = g2;
  }

  float f = 0.0f;
  #pragma unroll
  for (int i = 0; i < 8; ++i) {
    int col = i * 256 + tid;
    if (col < Vdim) {
      float p1 = expf(v1[i] - c1);
      float p2 = expf(v2[i] - c2);
      f += (p1 - p2) * (v1[i] - v2[i]);
    }
  }
  __syncthreads();
  f = waveSum(f);
  if (lane == 0) red[wave] = f;
  __syncthreads();
  if (tid == 0 && t < lens[bp]) {
    atomicAdd(&accum[1], 0.5f * (red[0] + red[1] + red[2] + red[3]));
  }
}

// ---------------- K4: CTC forward scan, one wave per sequence --------------
// LINEAR-space recurrence: zero transcendentals per step (log version: 10).
// Dynamic range managed by (a) zeroed G probs for states > end (see K3),
// (b) exact kill of states that can no longer reach the readout states
//     (s < end-1-2*steps_remaining) at every rescale, and
// (c) an exact power-of-2 rescale every 4 steps targeting max ~= 2^100.
// Final live band is <= 8 states (~120 bits spread) -> readout >= ~2^-64
// after scaling: no flush (round-1 inf), no overflow (growth <= 3^4 per
// rescale period -> max < 2^107). Rescale/kill is exact w.r.t. the readout,
// including for frozen (t >= len) alphas (invariant a*2^logScale preserved).
// 16-deep load pipeline + sched_barrier(0) fence retained.
#define PFD 16

#define DECL_S(i) float s##i##x, s##i##y, s##i##b;
#define DECL_N(i) float n##i##x, n##i##y, n##i##b;
#define PRIME(i) { float4 v = *(const float4*)(gb + (size_t)(1 + i) * GROW + 4 * lane); \
    s##i##x = v.x; s##i##y = v.y; s##i##b = v.z; }
#define LOADN(i) { int tp = t + (i) + PFD; tp = (tp < Tlen) ? tp : (Tlen - 1);\
    float4 v = *(const float4*)(gb + (size_t)tp * GROW + 4 * lane);           \
    n##i##x = v.x; n##i##y = v.y; n##i##b = v.z; }

// unconditional step (main loop: every t here satisfies t < len)
#define COMPU(i) {                                                            \
    float pX = s##i##x, pY = s##i##y, pB = s##i##b;                           \
    float p3 = shiftup1(a3, 0.0f);                                            \
    float n0 = (a0 + p3) * pB;                                                \
    float n1 = (a1 + a0 + (skip1 ? p3 : 0.0f)) * pX;                          \
    float n2 = (a2 + a1) * pB;                                                \
    float n3 = (a3 + a2 + (skip3 ? a1 : 0.0f)) * pY;                          \
    a0 = n0; a1 = n1; a2 = n2; a3 = n3;                                       \
    s##i##x = n##i##x; s##i##y = n##i##y; s##i##b = n##i##b; }

// guarded step (tail: freeze once past this sequence's input length)
#define COMPA(i) {                                                            \
    float pX = s##i##x, pY = s##i##y, pB = s##i##b;                           \
    float p3 = shiftup1(a3, 0.0f);                                            \
    float n0 = (a0 + p3) * pB;                                                \
    float n1 = (a1 + a0 + (skip1 ? p3 : 0.0f)) * pX;                          \
    float n2 = (a2 + a1) * pB;                                                \
    float n3 = (a3 + a2 + (skip3 ? a1 : 0.0f)) * pY;                          \
    bool act = (t + (i)) < len;                                               \
    a0 = act ? n0 : a0; a1 = act ? n1 : a1;                                   \
    a2 = act ? n2 : a2; a3 = act ? n3 : a3;                                   \
    s##i##x = n##i##x; s##i##y = n##i##y; s##i##b = n##i##b; }

// DPP wave-max step: bound_ctrl=true fills invalid lanes with 0 (all a >= 0)
#define DPPMAX(m, ctrl) { int _r = __builtin_amdgcn_update_dpp(0,              \
      __float_as_int(m), ctrl, 0xF, 0xF, true);                               \
    m = fmaxf(m, __int_as_float(_r)); }

// Exact kill of states that cannot reach the readout, then exact power-of-2
// rescale pinning the wave max at ~2^100; logScale tracks the total scale.
#define RESCALE_KILL(tdone) {                                                 \
    int R = len - 1 - (tdone); R = R < 0 ? 0 : R;                             \
    int lo = end1 - 2 * R;                                                    \
    a0 = (base4 + 0 >= lo) ? a0 : 0.0f;                                       \
    a1 = (base4 + 1 >= lo) ? a1 : 0.0f;                                       \
    a2 = (base4 + 2 >= lo) ? a2 : 0.0f;                                       \
    a3 = (base4 + 3 >= lo) ? a3 : 0.0f;                                       \
    float m = fmaxf(fmaxf(a0, a1), fmaxf(a2, a3));                            \
    DPPMAX(m, 0x111) DPPMAX(m, 0x112) DPPMAX(m, 0x114) DPPMAX(m, 0x118)       \
    DPPMAX(m, 0x142) DPPMAX(m, 0x143)                                         \
    uint32_t mb = (uint32_t)__builtin_amdgcn_readlane(__float_as_int(m), 63); \
    int e = (int)((mb >> 23) & 0xffu);                                        \
    int sh = 227 - e;                                                         \
    sh = sh > 127 ? 127 : (sh < -126 ? -126 : sh);                            \
    float sc = __uint_as_float((uint32_t)(sh + 127) << 23);                   \
    a0 *= sc; a1 *= sc; a2 *= sc; a3 *= sc;                                   \
    logScale -= sh; }

__global__ __launch_bounds__(64, 1) void ctc_kernel(const float* __restrict__ G,
                                                    const int* __restrict__ targets,
                                                    const int* __restrict__ lens,
                                                    const int* __restrict__ tlens,
                                                    float* __restrict__ accum) {
  int b = blockIdx.x;
  int lane = threadIdx.x;
  const int* tgt = targets + b * Udim;
  int i1 = min(2 * lane, Udim - 1);
  int i3 = min(2 * lane + 1, Udim - 1);
  int l1 = tgt[i1];
  int l3 = tgt[i3];
  int lm1 = tgt[min(max(2 * lane - 1, 0), Udim - 1)];
  bool skip1 = (lane >= 1) && (l1 != lm1);
  bool skip3 = (l3 != l1);
  int len = lens[b];
  int tl = tlens[b];
  const int end1 = 2 * tl - 1;       // readout states are end1 and end1+1
  const int base4 = 4 * lane;        // this lane owns states base4..base4+3
  const float* gb = G + (size_t)b * Tlen * GROW;

  // t=0 init (linear space): lane0's float4 = {p(tgt0), p(tgt1), blank, 0}
  float4 v0 = *(const float4*)(gb + 4 * lane);
  float a0 = (lane == 0) ? v0.z : 0.0f;
  float a1 = (lane == 0) ? v0.x : 0.0f;
  float a2 = 0.0f, a3 = 0.0f;
  int logScale = 0;

  DECL_S(0)  DECL_S(1)  DECL_S(2)  DECL_S(3)
  DECL_S(4)  DECL_S(5)  DECL_S(6)  DECL_S(7)
  DECL_S(8)  DECL_S(9)  DECL_S(10) DECL_S(11)
  DECL_S(12) DECL_S(13) DECL_S(14) DECL_S(15)
  DECL_N(0)  DECL_N(1)  DECL_N(2)  DECL_N(3)
  DECL_N(4)  DECL_N(5)  DECL_N(6)  DECL_N(7)
  DECL_N(8)  DECL_N(9)  DECL_N(10) DECL_N(11)
  DECL_N(12) DECL_N(13) DECL_N(14) DECL_N(15)

  PRIME(0)  PRIME(1)  PRIME(2)  PRIME(3)
  PRIME(4)  PRIME(5)  PRIME(6)  PRIME(7)
  PRIME(8)  PRIME(9)  PRIME(10) PRIME(11)
  PRIME(12) PRIME(13) PRIME(14) PRIME(15)

  int steps = len - 1;               // recurrence covers t = 1 .. len-1
  int mainN = steps & ~(PFD - 1);    // floor to multiple of 16: no freeze checks
  int t = 1;
  for (int blk = 0; blk < mainN; blk += PFD) {
    // batch-issue all 16 refill loads...
    LOADN(0)  LOADN(1)  LOADN(2)  LOADN(3)
    LOADN(4)  LOADN(5)  LOADN(6)  LOADN(7)
    LOADN(8)  LOADN(9)  LOADN(10) LOADN(11)
    LOADN(12) LOADN(13) LOADN(14) LOADN(15)
    // ...and FENCE: scheduler may not sink them past this point.
    __builtin_amdgcn_sched_barrier(0);
    COMPU(0)  COMPU(1)  COMPU(2)  COMPU(3)
    RESCALE_KILL(t + 3)
    COMPU(4)  COMPU(5)  COMPU(6)  COMPU(7)
    RESCALE_KILL(t + 7)
    COMPU(8)  COMPU(9)  COMPU(10) COMPU(11)
    RESCALE_KILL(t + 11)
    COMPU(12) COMPU(13) COMPU(14) COMPU(15)
    RESCALE_KILL(t + 15)
    t += PFD;
  }
  {
    // tail block of 16 with per-step freeze (covers remaining steps < 16)
    LOADN(0)  LOADN(1)  LOADN(2)  LOADN(3)
    LOADN(4)  LOADN(5)  LOADN(6)  LOADN(7)
    LOADN(8)  LOADN(9)  LOADN(10) LOADN(11)
    LOADN(12) LOADN(13) LOADN(14) LOADN(15)
    __builtin_amdgcn_sched_barrier(0);
    COMPA(0)  COMPA(1)  COMPA(2)  COMPA(3)
    RESCALE_KILL(t + 3)
    COMPA(4)  COMPA(5)  COMPA(6)  COMPA(7)
    RESCALE_KILL(t + 7)
    COMPA(8)  COMPA(9)  COMPA(10) COMPA(11)
    RESCALE_KILL(t + 11)
    COMPA(12) COMPA(13) COMPA(14) COMPA(15)
    RESCALE_KILL(t + 15)
    t += PFD;
  }

  __shared__ float fin[256];
  fin[4 * lane + 0] = a0;
  fin[4 * lane + 1] = a1;
  fin[4 * lane + 2] = a2;
  fin[4 * lane + 3] = a3;
  __syncthreads();
  if (lane == 0) {
    int end = 2 * tl;
    float sum = fin[end] + fin[end - 1];
    float loss = -LN2 * (log2f(sum) + (float)logScale);
    atomicAdd(&accum[0], 0.5f * loss);
  }
}

// ---------------- K5: finalize to FP32 output ------------------------------
__global__ void finalize_kernel(const float* __restrict__ accum, float* __restrict__ out) {
  if (threadIdx.x == 0) {
    out[0] = accum[0];
    out[1] = accum[1];
  }
}

extern "C" void kernel_launch(void* const* d_in, const int* in_sizes, int n_in,
                              void* d_out, int out_size, void* d_ws, size_t ws_size,
                              hipStream_t stream) {
  const float* enc = (const float*)d_in[0];
  const float* W = (const float*)d_in[1];
  const float* bias = (const float*)d_in[2];
  const int* lens = (const int*)d_in[3];
  const int* targets = (const int*)d_in[4];
  const int* tlens = (const int*)d_in[5];

  char* ws = (char*)d_ws;
  u16* a_bf = (u16*)(ws + WS_ABF);
  u16* w_bf = (u16*)(ws + WS_WBF);
  u16* Zb   = (u16*)(ws + WS_Z);
  float* Gp  = (float*)(ws + WS_G);   // aliases a_bf (dead after gemm)
  float* accum = (float*)(ws + WS_ACC);

  hipLaunchKernelGGL(convert_kernel, dim3(1024), dim3(256), 0, stream,
                     (const float4*)enc, (const float4*)W, (uint4*)a_bf, (uint4*)w_bf, accum);
  hipLaunchKernelGGL(gemm_kernel, dim3(16, 250), dim3(256), 0, stream,
                     a_bf, w_bf, Zb);
  hipLaunchKernelGGL(cr_stats_kernel, dim3(16, 1000), dim3(256), 0, stream,
                     Zb, bias, lens, targets, tlens, Gp, accum);
  hipLaunchKernelGGL(ctc_kernel, dim3(Bsz), dim3(64), 0, stream,
                     Gp, targets, lens, tlens, accum);
  hipLaunchKernelGGL(finalize_kernel, dim3(1), dim3(64), 0, stream,
                     accum, (float*)d_out);
}

// Round 5
// 416.602 us; speedup vs baseline: 1.4248x; 1.1025x over previous
//
#include <hip/hip_runtime.h>
#include <hip/hip_bf16.h>
#include <cstdint>

#define NEG (-1.0e30f)
#define INVLN2 1.44269504088896340736f
#define LN2    0.69314718055994530942f

typedef unsigned short u16;
typedef __attribute__((ext_vector_type(8))) short short8;
typedef __attribute__((ext_vector_type(4))) float f32x4;

typedef const __attribute__((address_space(1))) void cg_void;
typedef __attribute__((address_space(3))) void lds_void;

// dims
#define Bsz   32
#define Tlen  1000
#define Cdim  512
#define Vdim  2000
#define Udim  100
#define Mrows (Bsz * Tlen)   // 32000
#define Npad  2048
#define GROW  256            // G row stride in floats (1024 B): lane i owns
                             // float4 {p(tgt[2i]), p(tgt[2i+1]), p(blank), 0} (LINEAR probs)

// ws layout (bytes). G (32.768 MB) aliases a_bf exactly (dead after gemm).
#define WS_ABF 0u
#define WS_G   0u
#define WS_WBF 32768000u                    // a_bf/G: 32000*1024
#define WS_Z   (WS_WBF + 2097152u)          // w_bf: 2048*512*2
#define WS_ACC (WS_Z + 128000000u)          // Z: 32000*2000*2; then accum: 2 floats

__device__ inline u16 f2bf(float x) {
  uint32_t u = __float_as_uint(x);
  uint32_t r = (u + 0x7fffu + ((u >> 16) & 1u)) >> 16;
  return (u16)r;
}
__device__ inline float bf2f(u16 u) {
  return __uint_as_float(((uint32_t)u) << 16);
}

// ---- DPP wave64 reductions (pure VALU, no LDS). Result valid in lane 63. ----
// ctrl operand of update_dpp must be a literal constant (round-3 compile
// failure: array-indexed ctrl doesn't constant-fold) -> per-stage macros.
#define DPP_MAX_STAGE(m, ctrl) { \
    int _r = __builtin_amdgcn_update_dpp(__float_as_int(m), __float_as_int(m), \
                                         ctrl, 0xF, 0xF, false); \
    m = fmaxf(m, __int_as_float(_r)); }
#define DPP_SUM_STAGE(v, ctrl) { \
    int _r = __builtin_amdgcn_update_dpp(0, __float_as_int(v), \
                                         ctrl, 0xF, 0xF, true); \
    v += __int_as_float(_r); }

__device__ inline float dppMax64(float m) {
  DPP_MAX_STAGE(m, 0x111) DPP_MAX_STAGE(m, 0x112) DPP_MAX_STAGE(m, 0x114)
  DPP_MAX_STAGE(m, 0x118) DPP_MAX_STAGE(m, 0x142) DPP_MAX_STAGE(m, 0x143)
  return m;  // valid in lane 63
}
__device__ inline float dppSum64(float v) {
  DPP_SUM_STAGE(v, 0x111) DPP_SUM_STAGE(v, 0x112) DPP_SUM_STAGE(v, 0x114)
  DPP_SUM_STAGE(v, 0x118) DPP_SUM_STAGE(v, 0x142) DPP_SUM_STAGE(v, 0x143)
  return v;  // valid in lane 63
}

// shift value from lane-1 into this lane via DPP wave_shr:1 (VALU, no LDS).
__device__ inline float shiftup1(float x, float fill) {
  int r = __builtin_amdgcn_update_dpp(__float_as_int(fill), __float_as_int(x),
                                      0x138, 0xF, 0xF, false);
  return __int_as_float(r);
}

// ---------------- K1: fp32 -> bf16 conversion, vectorized ------------------
__global__ void convert_kernel(const float4* __restrict__ enc4, const float4* __restrict__ W4,
                               uint4* __restrict__ a4, uint4* __restrict__ w4,
                               float* __restrict__ accum) {
  int idx = blockIdx.x * blockDim.x + threadIdx.x;
  int stride = gridDim.x * blockDim.x;
  if (idx == 0) { accum[0] = 0.0f; accum[1] = 0.0f; }
  const int nA = Mrows * Cdim / 8;
  const int nW = Vdim * Cdim / 8;
  const int nWp = Npad * Cdim / 8;
  for (int i = idx; i < nA; i += stride) {
    float4 x = enc4[2 * i], y = enc4[2 * i + 1];
    uint4 o;
    o.x = (uint32_t)f2bf(x.x) | ((uint32_t)f2bf(x.y) << 16);
    o.y = (uint32_t)f2bf(x.z) | ((uint32_t)f2bf(x.w) << 16);
    o.z = (uint32_t)f2bf(y.x) | ((uint32_t)f2bf(y.y) << 16);
    o.w = (uint32_t)f2bf(y.z) | ((uint32_t)f2bf(y.w) << 16);
    a4[i] = o;
  }
  for (int i = idx; i < nWp; i += stride) {
    uint4 o = {0, 0, 0, 0};
    if (i < nW) {
      float4 x = W4[2 * i], y = W4[2 * i + 1];
      o.x = (uint32_t)f2bf(x.x) | ((uint32_t)f2bf(x.y) << 16);
      o.y = (uint32_t)f2bf(x.z) | ((uint32_t)f2bf(x.w) << 16);
      o.z = (uint32_t)f2bf(y.x) | ((uint32_t)f2bf(y.y) << 16);
      o.w = (uint32_t)f2bf(y.z) | ((uint32_t)f2bf(y.w) << 16);
    }
    w4[i] = o;
  }
}

// ---------------- K2: bf16 GEMM (A: 32000x512, W: 2048x512, C = A*W^T) -----
__global__ __launch_bounds__(256) void gemm_kernel(const u16* __restrict__ A,
                                                   const u16* __restrict__ Wb,
                                                   u16* __restrict__ Z) {
  __shared__ __attribute__((aligned(16))) u16 As[128 * 64];
  __shared__ __attribute__((aligned(16))) u16 Bs[128 * 64];
  const int tid = threadIdx.x;
  const int wave = tid >> 6;
  const int lane = tid & 63;
  const int nBase = blockIdx.x * 128;
  const int mBase = blockIdx.y * 128;
  const int m_lane = lane & 15;
  const int quad = lane >> 4;

  f32x4 acc[4][4];
  const f32x4 zero4 = {0.0f, 0.0f, 0.0f, 0.0f};
  #pragma unroll
  for (int i = 0; i < 4; ++i)
    #pragma unroll
    for (int j = 0; j < 4; ++j) acc[i][j] = zero4;

  for (int k0 = 0; k0 < Cdim; k0 += 64) {
    #pragma unroll
    for (int r = 0; r < 4; ++r) {
      int u = r * 256 + tid;
      int g = u >> 3;
      int q = (u & 7) ^ (g & 7);
      const u16* gpA = A + ((size_t)(mBase + g) << 9) + (k0 + (q << 3));
      __builtin_amdgcn_global_load_lds((cg_void*)gpA, (lds_void*)&As[(r * 4 + wave) * 512],
                                       16, 0, 0);
      const u16* gpB = Wb + ((size_t)(nBase + g) << 9) + (k0 + (q << 3));
      __builtin_amdgcn_global_load_lds((cg_void*)gpB, (lds_void*)&Bs[(r * 4 + wave) * 512],
                                       16, 0, 0);
    }
    __syncthreads();
    #pragma unroll
    for (int kk = 0; kk < 2; ++kk) {
      short8 af[4], bfv[4];
      #pragma unroll
      for (int mi = 0; mi < 4; ++mi) {
        int row = (wave >> 1) * 64 + mi * 16 + m_lane;
        int q = (kk * 4 + quad) ^ (row & 7);
        af[mi] = *(const short8*)&As[row * 64 + (q << 3)];
      }
      #pragma unroll
      for (int ni = 0; ni < 4; ++ni) {
        int col = (wave & 1) * 64 + ni * 16 + m_lane;
        int q = (kk * 4 + quad) ^ (col & 7);
        bfv[ni] = *(const short8*)&Bs[col * 64 + (q << 3)];
      }
      #pragma unroll
      for (int mi = 0; mi < 4; ++mi)
        #pragma unroll
        for (int ni = 0; ni < 4; ++ni)
          acc[mi][ni] = __builtin_amdgcn_mfma_f32_16x16x32_bf16(af[mi], bfv[ni],
                                                                acc[mi][ni], 0, 0, 0);
    }
    __syncthreads();
  }
  #pragma unroll
  for (int ni = 0; ni < 4; ++ni) {
    int col = nBase + (wave & 1) * 64 + ni * 16 + m_lane;
    if (col < Vdim) {
      #pragma unroll
      for (int mi = 0; mi < 4; ++mi) {
        int row0 = mBase + (wave >> 1) * 64 + mi * 16 + quad * 4;
        #pragma unroll
        for (int rg = 0; rg < 4; ++rg)
          Z[(size_t)(row0 + rg) * Vdim + col] = f2bf(acc[mi][ni][rg]);
      }
    }
  }
}

// ---------------- K3: fused softmax stats + CR loss + CTC gather -----------
// (1) whole-block early exit for t >= len (lens[bp] == lens[bp+16] by
// construction; KL masked out and G rows unread for t >= len -- the scan
// only touches them as discarded frozen prefetches); (2) KL pass reuses
// e = expf(v-M) from the sum pass via p = e/S (exact), halving expf count;
// (3) DPP reductions (lane 63) instead of __shfl_down LDS chains.
__global__ __launch_bounds__(256) void cr_stats_kernel(const u16* __restrict__ Z,
                                                       const float* __restrict__ bias,
                                                       const int* __restrict__ lens,
                                                       const int* __restrict__ targets,
                                                       const int* __restrict__ tlens,
                                                       float* __restrict__ G,
                                                       float* __restrict__ accum) {
  int bp = blockIdx.x;   // 0..15
  int t = blockIdx.y;    // 0..999
  if (t >= lens[bp]) return;   // dead block: nothing it makes is consumed
  int tid = threadIdx.x;
  int wave = tid >> 6, lane = tid & 63;
  size_t r1 = (size_t)bp * Tlen + t;
  size_t r2 = r1 + (size_t)16 * Tlen;
  const u16* z1 = Z + r1 * Vdim;
  const u16* z2 = Z + r2 * Vdim;

  __shared__ float ls1[Vdim];
  __shared__ float ls2[Vdim];
  __shared__ float red[8];

  float v1[8], v2[8], e1[8], e2[8];
  float mx1 = NEG, mx2 = NEG;
  #pragma unroll
  for (int i = 0; i < 8; ++i) {
    int col = i * 256 + tid;
    if (col < Vdim) {
      float bb = bias[col];
      v1[i] = bf2f(z1[col]) + bb;
      v2[i] = bf2f(z2[col]) + bb;
      ls1[col] = v1[i];
      ls2[col] = v2[i];
      mx1 = fmaxf(mx1, v1[i]);
      mx2 = fmaxf(mx2, v2[i]);
    } else { v1[i] = NEG; v2[i] = NEG; }
  }
  float w1 = dppMax64(mx1), w2 = dppMax64(mx2);
  if (lane == 63) { red[wave] = w1; red[4 + wave] = w2; }
  __syncthreads();
  float M1 = fmaxf(fmaxf(red[0], red[1]), fmaxf(red[2], red[3]));
  float M2 = fmaxf(fmaxf(red[4], red[5]), fmaxf(red[6], red[7]));
  __syncthreads();
  float s1 = 0.0f, s2 = 0.0f;
  #pragma unroll
  for (int i = 0; i < 8; ++i) {
    e1[i] = expf(v1[i] - M1);   // 0 for padded cols (v = NEG)
    e2[i] = expf(v2[i] - M2);
    s1 += e1[i];
    s2 += e2[i];
  }
  s1 = dppSum64(s1); s2 = dppSum64(s2);
  if (lane == 63) { red[wave] = s1; red[4 + wave] = s2; }
  __syncthreads();
  float S1 = red[0] + red[1] + red[2] + red[3];
  float S2 = red[4] + red[5] + red[6] + red[7];
  float c1 = M1 + logf(S1);
  float c2 = M2 + logf(S2);
  float inv1 = 1.0f / S1;
  float inv2 = 1.0f / S2;

  if (tid < 64) {
    int i1 = min(2 * tid, Udim - 1);
    int i3 = min(2 * tid + 1, Udim - 1);
    int t1a = targets[bp * Udim + i1];
    int t1b = targets[bp * Udim + i3];
    int t2a = targets[(bp + 16) * Udim + i1];
    int t2b = targets[(bp + 16) * Udim + i3];
    int tl1 = tlens[bp];
    int tl2 = tlens[bp + 16];
    // LINEAR probabilities; labels past this sequence's target length -> 0
    // (keeps lattice states s > 2*tl exactly 0 in the scan).
    float4 g1 = {(2 * tid < tl1) ? expf(ls1[t1a] - c1) : 0.0f,
                 (2 * tid + 1 < tl1) ? expf(ls1[t1b] - c1) : 0.0f,
                 expf(ls1[0] - c1), 0.0f};
    float4 g2 = {(2 * tid < tl2) ? expf(ls2[t2a] - c2) : 0.0f,
                 (2 * tid + 1 < tl2) ? expf(ls2[t2b] - c2) : 0.0f,
                 expf(ls2[0] - c2), 0.0f};
    *(float4*)(G + r1 * GROW + 4 * tid) = g1;
    *(float4*)(G + r2 * GROW + 4 * tid) = g2;
  }

  float f = 0.0f;
  #pragma unroll
  for (int i = 0; i < 8; ++i) {
    // p = expf(v - c) == e * (1/S), exactly; padded cols: (0-0)*(0) = 0.
    float p1 = e1[i] * inv1;
    float p2 = e2[i] * inv2;
    f += (p1 - p2) * (v1[i] - v2[i]);
  }
  __syncthreads();
  f = dppSum64(f);
  if (lane == 63) red[wave] = f;
  __syncthreads();
  if (tid == 0) {
    atomicAdd(&accum[1], 0.5f * (red[0] + red[1] + red[2] + red[3]));
  }
}

// ---------------- K4: CTC forward scan, one wave per sequence --------------
// LINEAR-space recurrence -- issue-count cuts (the kernel runs 1 wave/SIMD,
// so it is ISSUE-bound: every instruction ~2 cyc serial):
//  - 32-step superblock with two register banks (A/B) -> no s<-n copy movs
//  - skip conditions as float masks -> fma instead of cndmask+add
//  - rescale+kill every 8 steps: growth <= 3^8 ~ 2^12.7 off the 2^100 pin,
//    no overflow; flush headroom (~226 bits below max) intact
//  - no row clamp on prefetch: over-reads (< 48 KB past a 1 MB chunk) stay
//    inside the mapped workspace; values are discarded by tail freeze masks.
#define DECL3(p, i) float p##i##x, p##i##y, p##i##b;
#define LOADR(p, i, row) { float4 v = *(const float4*)(gb + (size_t)(row) * GROW + 4 * lane); \
    p##i##x = v.x; p##i##y = v.y; p##i##b = v.z; }

// unconditional step (main loop: every step here satisfies t < len)
#define COMPU(p, i) { \
    float pX = p##i##x, pY = p##i##y, pB = p##i##b; \
    float p3 = shiftup1(a3, 0.0f); \
    float t01 = a1 + a0; \
    float t23 = a3 + a2; \
    float n0 = (a0 + p3) * pB; \
    float n1 = fmaf(p3, fm1, t01) * pX; \
    float n2 = (a2 + a1) * pB; \
    float n3 = fmaf(a1, fm3, t23) * pY; \
    a0 = n0; a1 = n1; a2 = n2; a3 = n3; }

// guarded step (tail: freeze once past this sequence's input length)
#define COMPA(p, i, off) { \
    float pX = p##i##x, pY = p##i##y, pB = p##i##b; \
    float p3 = shiftup1(a3, 0.0f); \
    float t01 = a1 + a0; \
    float t23 = a3 + a2; \
    float n0 = (a0 + p3) * pB; \
    float n1 = fmaf(p3, fm1, t01) * pX; \
    float n2 = (a2 + a1) * pB; \
    float n3 = fmaf(a1, fm3, t23) * pY; \
    bool act = (t + (off)) < len; \
    a0 = act ? n0 : a0; a1 = act ? n1 : a1; \
    a2 = act ? n2 : a2; a3 = act ? n3 : a3; }

// DPP wave-max step: bound_ctrl=true fills invalid lanes with 0 (all a >= 0)
#define DPPMAX(m, ctrl) { int _r = __builtin_amdgcn_update_dpp(0,              \
      __float_as_int(m), ctrl, 0xF, 0xF, true);                               \
    m = fmaxf(m, __int_as_float(_r)); }

// Exact kill of states that cannot reach the readout, then exact power-of-2
// rescale pinning the wave max at ~2^100; logScale tracks the total scale.
#define RESCALE_KILL(tdone) {                                                 \
    int R = len - 1 - (tdone); R = R < 0 ? 0 : R;                             \
    int lo = end1 - 2 * R;                                                    \
    a0 = (base4 + 0 >= lo) ? a0 : 0.0f;                                       \
    a1 = (base4 + 1 >= lo) ? a1 : 0.0f;                                       \
    a2 = (base4 + 2 >= lo) ? a2 : 0.0f;                                       \
    a3 = (base4 + 3 >= lo) ? a3 : 0.0f;                                       \
    float m = fmaxf(fmaxf(a0, a1), fmaxf(a2, a3));                            \
    DPPMAX(m, 0x111) DPPMAX(m, 0x112) DPPMAX(m, 0x114) DPPMAX(m, 0x118)       \
    DPPMAX(m, 0x142) DPPMAX(m, 0x143)                                         \
    uint32_t mb = (uint32_t)__builtin_amdgcn_readlane(__float_as_int(m), 63); \
    int e = (int)((mb >> 23) & 0xffu);                                        \
    int sh = 227 - e;                                                         \
    sh = sh > 127 ? 127 : (sh < -126 ? -126 : sh);                            \
    float sc = __uint_as_float((uint32_t)(sh + 127) << 23);                   \
    a0 *= sc; a1 *= sc; a2 *= sc; a3 *= sc;                                   \
    logScale -= sh; }

__global__ __launch_bounds__(64, 1) void ctc_kernel(const float* __restrict__ G,
                                                    const int* __restrict__ targets,
                                                    const int* __restrict__ lens,
                                                    const int* __restrict__ tlens,
                                                    float* __restrict__ accum) {
  int b = blockIdx.x;
  int lane = threadIdx.x;
  const int* tgt = targets + b * Udim;
  int i1 = min(2 * lane, Udim - 1);
  int i3 = min(2 * lane + 1, Udim - 1);
  int l1 = tgt[i1];
  int l3 = tgt[i3];
  int lm1 = tgt[min(max(2 * lane - 1, 0), Udim - 1)];
  const float fm1 = ((lane >= 1) && (l1 != lm1)) ? 1.0f : 0.0f;  // skip1 mask
  const float fm3 = (l3 != l1) ? 1.0f : 0.0f;                    // skip3 mask
  int len = lens[b];
  int tl = tlens[b];
  const int end1 = 2 * tl - 1;       // readout states are end1 and end1+1
  const int base4 = 4 * lane;        // this lane owns states base4..base4+3
  const float* gb = G + (size_t)b * Tlen * GROW;

  // t=0 init (linear space): lane0's float4 = {p(tgt0), p(tgt1), blank, 0}
  float4 v0 = *(const float4*)(gb + 4 * lane);
  float a0 = (lane == 0) ? v0.z : 0.0f;
  float a1 = (lane == 0) ? v0.x : 0.0f;
  float a2 = 0.0f, a3 = 0.0f;
  int logScale = 0;

  DECL3(sA, 0)  DECL3(sA, 1)  DECL3(sA, 2)  DECL3(sA, 3)
  DECL3(sA, 4)  DECL3(sA, 5)  DECL3(sA, 6)  DECL3(sA, 7)
  DECL3(sA, 8)  DECL3(sA, 9)  DECL3(sA, 10) DECL3(sA, 11)
  DECL3(sA, 12) DECL3(sA, 13) DECL3(sA, 14) DECL3(sA, 15)
  DECL3(sB, 0)  DECL3(sB, 1)  DECL3(sB, 2)  DECL3(sB, 3)
  DECL3(sB, 4)  DECL3(sB, 5)  DECL3(sB, 6)  DECL3(sB, 7)
  DECL3(sB, 8)  DECL3(sB, 9)  DECL3(sB, 10) DECL3(sB, 11)
  DECL3(sB, 12) DECL3(sB, 13) DECL3(sB, 14) DECL3(sB, 15)

  // prime bank A with rows 1..16 (all valid: len >= 500)
  LOADR(sA, 0, 1)   LOADR(sA, 1, 2)   LOADR(sA, 2, 3)   LOADR(sA, 3, 4)
  LOADR(sA, 4, 5)   LOADR(sA, 5, 6)   LOADR(sA, 6, 7)   LOADR(sA, 7, 8)
  LOADR(sA, 8, 9)   LOADR(sA, 9, 10)  LOADR(sA, 10, 11) LOADR(sA, 11, 12)
  LOADR(sA, 12, 13) LOADR(sA, 13, 14) LOADR(sA, 14, 15) LOADR(sA, 15, 16)

  int steps = len - 1;               // recurrence covers t = 1 .. len-1
  int mainN = steps & ~31;           // floor to multiple of 32
  int t = 1;
  for (int blk = 0; blk < mainN; blk += 32) {
    // H0: refill bank B (rows t+16..t+31), consume bank A (steps t..t+15)
    LOADR(sB, 0, t + 16)  LOADR(sB, 1, t + 17)  LOADR(sB, 2, t + 18)  LOADR(sB, 3, t + 19)
    LOADR(sB, 4, t + 20)  LOADR(sB, 5, t + 21)  LOADR(sB, 6, t + 22)  LOADR(sB, 7, t + 23)
    LOADR(sB, 8, t + 24)  LOADR(sB, 9, t + 25)  LOADR(sB, 10, t + 26) LOADR(sB, 11, t + 27)
    LOADR(sB, 12, t + 28) LOADR(sB, 13, t + 29) LOADR(sB, 14, t + 30) LOADR(sB, 15, t + 31)
    __builtin_amdgcn_sched_barrier(0);
    COMPU(sA, 0)  COMPU(sA, 1)  COMPU(sA, 2)  COMPU(sA, 3)
    COMPU(sA, 4)  COMPU(sA, 5)  COMPU(sA, 6)  COMPU(sA, 7)
    RESCALE_KILL(t + 7)
    COMPU(sA, 8)  COMPU(sA, 9)  COMPU(sA, 10) COMPU(sA, 11)
    COMPU(sA, 12) COMPU(sA, 13) COMPU(sA, 14) COMPU(sA, 15)
    RESCALE_KILL(t + 15)
    // H1: refill bank A (rows t+32..t+47), consume bank B (steps t+16..t+31)
    LOADR(sA, 0, t + 32)  LOADR(sA, 1, t + 33)  LOADR(sA, 2, t + 34)  LOADR(sA, 3, t + 35)
    LOADR(sA, 4, t + 36)  LOADR(sA, 5, t + 37)  LOADR(sA, 6, t + 38)  LOADR(sA, 7, t + 39)
    LOADR(sA, 8, t + 40)  LOADR(sA, 9, t + 41)  LOADR(sA, 10, t + 42) LOADR(sA, 11, t + 43)
    LOADR(sA, 12, t + 44) LOADR(sA, 13, t + 45) LOADR(sA, 14, t + 46) LOADR(sA, 15, t + 47)
    __builtin_amdgcn_sched_barrier(0);
    COMPU(sB, 0)  COMPU(sB, 1)  COMPU(sB, 2)  COMPU(sB, 3)
    COMPU(sB, 4)  COMPU(sB, 5)  COMPU(sB, 6)  COMPU(sB, 7)
    RESCALE_KILL(t + 23)
    COMPU(sB, 8)  COMPU(sB, 9)  COMPU(sB, 10) COMPU(sB, 11)
    COMPU(sB, 12) COMPU(sB, 13) COMPU(sB, 14) COMPU(sB, 15)
    RESCALE_KILL(t + 31)
    t += 32;
  }
  {
    // tail: up to 32 guarded steps. Bank A holds rows t..t+15 (loaded by the
    // last H1); refill bank B for rows t+16..t+31 (over-reads are garbage,
    // discarded by the freeze masks).
    LOADR(sB, 0, t + 16)  LOADR(sB, 1, t + 17)  LOADR(sB, 2, t + 18)  LOADR(sB, 3, t + 19)
    LOADR(sB, 4, t + 20)  LOADR(sB, 5, t + 21)  LOADR(sB, 6, t + 22)  LOADR(sB, 7, t + 23)
    LOADR(sB, 8, t + 24)  LOADR(sB, 9, t + 25)  LOADR(sB, 10, t + 26) LOADR(sB, 11, t + 27)
    LOADR(sB, 12, t + 28) LOADR(sB, 13, t + 29) LOADR(sB, 14, t + 30) LOADR(sB, 15, t + 31)
    __builtin_amdgcn_sched_barrier(0);
    COMPA(sA, 0, 0)   COMPA(sA, 1, 1)   COMPA(sA, 2, 2)   COMPA(sA, 3, 3)
    COMPA(sA, 4, 4)   COMPA(sA, 5, 5)   COMPA(sA, 6, 6)   COMPA(sA, 7, 7)
    RESCALE_KILL(t + 7)
    COMPA(sA, 8, 8)   COMPA(sA, 9, 9)   COMPA(sA, 10, 10) COMPA(sA, 11, 11)
    COMPA(sA, 12, 12) COMPA(sA, 13, 13) COMPA(sA, 14, 14) COMPA(sA, 15, 15)
    RESCALE_KILL(t + 15)
    COMPA(sB, 0, 16)  COMPA(sB, 1, 17)  COMPA(sB, 2, 18)  COMPA(sB, 3, 19)
    COMPA(sB, 4, 20)  COMPA(sB, 5, 21)  COMPA(sB, 6, 22)  COMPA(sB, 7, 23)
    RESCALE_KILL(t + 23)
    COMPA(sB, 8, 24)  COMPA(sB, 9, 25)  COMPA(sB, 10, 26) COMPA(sB, 11, 27)
    COMPA(sB, 12, 28) COMPA(sB, 13, 29) COMPA(sB, 14, 30) COMPA(sB, 15, 31)
    RESCALE_KILL(t + 31)
  }

  __shared__ float fin[256];
  fin[4 * lane + 0] = a0;
  fin[4 * lane + 1] = a1;
  fin[4 * lane + 2] = a2;
  fin[4 * lane + 3] = a3;
  __syncthreads();
  if (lane == 0) {
    int end = 2 * tl;
    float sum = fin[end] + fin[end - 1];
    float loss = -LN2 * (log2f(sum) + (float)logScale);
    atomicAdd(&accum[0], 0.5f * loss);
  }
}

// ---------------- K5: finalize to FP32 output ------------------------------
__global__ void finalize_kernel(const float* __restrict__ accum, float* __restrict__ out) {
  if (threadIdx.x == 0) {
    out[0] = accum[0];
    out[1] = accum[1];
  }
}

extern "C" void kernel_launch(void* const* d_in, const int* in_sizes, int n_in,
                              void* d_out, int out_size, void* d_ws, size_t ws_size,
                              hipStream_t stream) {
  const float* enc = (const float*)d_in[0];
  const float* W = (const float*)d_in[1];
  const float* bias = (const float*)d_in[2];
  const int* lens = (const int*)d_in[3];
  const int* targets = (const int*)d_in[4];
  const int* tlens = (const int*)d_in[5];

  char* ws = (char*)d_ws;
  u16* a_bf = (u16*)(ws + WS_ABF);
  u16* w_bf = (u16*)(ws + WS_WBF);
  u16* Zb   = (u16*)(ws + WS_Z);
  float* Gp  = (float*)(ws + WS_G);   // aliases a_bf (dead after gemm)
  float* accum = (float*)(ws + WS_ACC);

  hipLaunchKernelGGL(convert_kernel, dim3(1024), dim3(256), 0, stream,
                     (const float4*)enc, (const float4*)W, (uint4*)a_bf, (uint4*)w_bf, accum);
  hipLaunchKernelGGL(gemm_kernel, dim3(16, 250), dim3(256), 0, stream,
                     a_bf, w_bf, Zb);
  hipLaunchKernelGGL(cr_stats_kernel, dim3(16, 1000), dim3(256), 0, stream,
                     Zb, bias, lens, targets, tlens, Gp, accum);
  hipLaunchKernelGGL(ctc_kernel, dim3(Bsz), dim3(64), 0, stream,
                     Gp, targets, lens, tlens, accum);
  hipLaunchKernelGGL(finalize_kernel, dim3(1), dim3(64), 0, stream,
                     accum, (float*)d_out);
}

// Round 6
// 306.107 us; speedup vs baseline: 1.9391x; 1.3610x over previous
//
#include <hip/hip_runtime.h>
#include <hip/hip_bf16.h>
#include <cstdint>

#define NEG (-1.0e30f)
#define INVLN2 1.44269504088896340736f
#define LN2    0.69314718055994530942f

typedef unsigned short u16;
typedef __attribute__((ext_vector_type(8))) short short8;
typedef __attribute__((ext_vector_type(4))) float f32x4;

typedef const __attribute__((address_space(1))) void cg_void;
typedef __attribute__((address_space(3))) void lds_void;

// dims
#define Bsz   32
#define Tlen  1000
#define Cdim  512
#define Vdim  2000
#define Udim  100
#define Mrows (Bsz * Tlen)   // 32000
#define Npad  2048
#define GROW  256            // G row stride in floats (1024 B): lane i owns
                             // float4 {p(tgt[2i]), p(tgt[2i+1]), p(blank), 0} (LINEAR probs)

// ws layout (bytes). G (32.768 MB) aliases a_bf exactly (dead after gemm).
// klp (64 KB, KL per-block partials) aliases w_bf (dead after gemm).
#define WS_ABF 0u
#define WS_G   0u
#define WS_WBF 32768000u                    // a_bf/G: 32000*1024
#define WS_KL  WS_WBF                       // 16*1000 floats, aliases w_bf
#define WS_Z   (WS_WBF + 2097152u)          // w_bf: 2048*512*2
#define WS_ACC (WS_Z + 128000000u)          // Z: 32000*2000*2; then accum: 2 floats

__device__ inline u16 f2bf(float x) {
  uint32_t u = __float_as_uint(x);
  uint32_t r = (u + 0x7fffu + ((u >> 16) & 1u)) >> 16;
  return (u16)r;
}
__device__ inline float bf2f(u16 u) {
  return __uint_as_float(((uint32_t)u) << 16);
}

// ---- DPP wave64 reductions (pure VALU, no LDS). Result valid in lane 63. ----
// ctrl operand of update_dpp must be a literal constant -> per-stage macros.
#define DPP_MAX_STAGE(m, ctrl) { \
    int _r = __builtin_amdgcn_update_dpp(__float_as_int(m), __float_as_int(m), \
                                         ctrl, 0xF, 0xF, false); \
    m = fmaxf(m, __int_as_float(_r)); }
#define DPP_SUM_STAGE(v, ctrl) { \
    int _r = __builtin_amdgcn_update_dpp(0, __float_as_int(v), \
                                         ctrl, 0xF, 0xF, true); \
    v += __int_as_float(_r); }

__device__ inline float dppMax64(float m) {
  DPP_MAX_STAGE(m, 0x111) DPP_MAX_STAGE(m, 0x112) DPP_MAX_STAGE(m, 0x114)
  DPP_MAX_STAGE(m, 0x118) DPP_MAX_STAGE(m, 0x142) DPP_MAX_STAGE(m, 0x143)
  return m;  // valid in lane 63
}
__device__ inline float dppSum64(float v) {
  DPP_SUM_STAGE(v, 0x111) DPP_SUM_STAGE(v, 0x112) DPP_SUM_STAGE(v, 0x114)
  DPP_SUM_STAGE(v, 0x118) DPP_SUM_STAGE(v, 0x142) DPP_SUM_STAGE(v, 0x143)
  return v;  // valid in lane 63
}

// shift value from lane-1 into this lane via DPP wave_shr:1 (VALU, no LDS).
__device__ inline float shiftup1(float x, float fill) {
  int r = __builtin_amdgcn_update_dpp(__float_as_int(fill), __float_as_int(x),
                                      0x138, 0xF, 0xF, false);
  return __int_as_float(r);
}

// ---------------- K1: fp32 -> bf16 conversion, vectorized ------------------
__global__ void convert_kernel(const float4* __restrict__ enc4, const float4* __restrict__ W4,
                               uint4* __restrict__ a4, uint4* __restrict__ w4,
                               float* __restrict__ accum) {
  int idx = blockIdx.x * blockDim.x + threadIdx.x;
  int stride = gridDim.x * blockDim.x;
  if (idx == 0) { accum[0] = 0.0f; accum[1] = 0.0f; }
  const int nA = Mrows * Cdim / 8;
  const int nW = Vdim * Cdim / 8;
  const int nWp = Npad * Cdim / 8;
  for (int i = idx; i < nA; i += stride) {
    float4 x = enc4[2 * i], y = enc4[2 * i + 1];
    uint4 o;
    o.x = (uint32_t)f2bf(x.x) | ((uint32_t)f2bf(x.y) << 16);
    o.y = (uint32_t)f2bf(x.z) | ((uint32_t)f2bf(x.w) << 16);
    o.z = (uint32_t)f2bf(y.x) | ((uint32_t)f2bf(y.y) << 16);
    o.w = (uint32_t)f2bf(y.z) | ((uint32_t)f2bf(y.w) << 16);
    a4[i] = o;
  }
  for (int i = idx; i < nWp; i += stride) {
    uint4 o = {0, 0, 0, 0};
    if (i < nW) {
      float4 x = W4[2 * i], y = W4[2 * i + 1];
      o.x = (uint32_t)f2bf(x.x) | ((uint32_t)f2bf(x.y) << 16);
      o.y = (uint32_t)f2bf(x.z) | ((uint32_t)f2bf(x.w) << 16);
      o.z = (uint32_t)f2bf(y.x) | ((uint32_t)f2bf(y.y) << 16);
      o.w = (uint32_t)f2bf(y.z) | ((uint32_t)f2bf(y.w) << 16);
    }
    w4[i] = o;
  }
}

// ---------------- K2: bf16 GEMM (A: 32000x512, W: 2048x512, C = A*W^T) -----
__global__ __launch_bounds__(256) void gemm_kernel(const u16* __restrict__ A,
                                                   const u16* __restrict__ Wb,
                                                   u16* __restrict__ Z) {
  __shared__ __attribute__((aligned(16))) u16 As[128 * 64];
  __shared__ __attribute__((aligned(16))) u16 Bs[128 * 64];
  const int tid = threadIdx.x;
  const int wave = tid >> 6;
  const int lane = tid & 63;
  const int nBase = blockIdx.x * 128;
  const int mBase = blockIdx.y * 128;
  const int m_lane = lane & 15;
  const int quad = lane >> 4;

  f32x4 acc[4][4];
  const f32x4 zero4 = {0.0f, 0.0f, 0.0f, 0.0f};
  #pragma unroll
  for (int i = 0; i < 4; ++i)
    #pragma unroll
    for (int j = 0; j < 4; ++j) acc[i][j] = zero4;

  for (int k0 = 0; k0 < Cdim; k0 += 64) {
    #pragma unroll
    for (int r = 0; r < 4; ++r) {
      int u = r * 256 + tid;
      int g = u >> 3;
      int q = (u & 7) ^ (g & 7);
      const u16* gpA = A + ((size_t)(mBase + g) << 9) + (k0 + (q << 3));
      __builtin_amdgcn_global_load_lds((cg_void*)gpA, (lds_void*)&As[(r * 4 + wave) * 512],
                                       16, 0, 0);
      const u16* gpB = Wb + ((size_t)(nBase + g) << 9) + (k0 + (q << 3));
      __builtin_amdgcn_global_load_lds((cg_void*)gpB, (lds_void*)&Bs[(r * 4 + wave) * 512],
                                       16, 0, 0);
    }
    __syncthreads();
    #pragma unroll
    for (int kk = 0; kk < 2; ++kk) {
      short8 af[4], bfv[4];
      #pragma unroll
      for (int mi = 0; mi < 4; ++mi) {
        int row = (wave >> 1) * 64 + mi * 16 + m_lane;
        int q = (kk * 4 + quad) ^ (row & 7);
        af[mi] = *(const short8*)&As[row * 64 + (q << 3)];
      }
      #pragma unroll
      for (int ni = 0; ni < 4; ++ni) {
        int col = (wave & 1) * 64 + ni * 16 + m_lane;
        int q = (kk * 4 + quad) ^ (col & 7);
        bfv[ni] = *(const short8*)&Bs[col * 64 + (q << 3)];
      }
      #pragma unroll
      for (int mi = 0; mi < 4; ++mi)
        #pragma unroll
        for (int ni = 0; ni < 4; ++ni)
          acc[mi][ni] = __builtin_amdgcn_mfma_f32_16x16x32_bf16(af[mi], bfv[ni],
                                                                acc[mi][ni], 0, 0, 0);
    }
    __syncthreads();
  }
  #pragma unroll
  for (int ni = 0; ni < 4; ++ni) {
    int col = nBase + (wave & 1) * 64 + ni * 16 + m_lane;
    if (col < Vdim) {
      #pragma unroll
      for (int mi = 0; mi < 4; ++mi) {
        int row0 = mBase + (wave >> 1) * 64 + mi * 16 + quad * 4;
        #pragma unroll
        for (int rg = 0; rg < 4; ++rg)
          Z[(size_t)(row0 + rg) * Vdim + col] = f2bf(acc[mi][ni][rg]);
      }
    }
  }
}

// ---------------- K3: fused softmax stats + CR loss + CTC gather -----------
// Round-6: (1) the per-block atomicAdd(accum[1]) -- ~12000 same-address
// atomics at ~14 ns each WERE the kernel's 166 us floor (r2->r5: halving
// VALU+memory work moved duration by 2%) -- replaced by an uncontended
// per-block store to klp[bp*Tlen+t]; dead blocks store 0. Reduction moved
// to finalize. (2) Z/bias loads vectorized: thread owns 8 contiguous cols
// (short8 + 2x float4), 24 scalar loads -> 4 vector loads, 1 KB/wave-inst.
__global__ __launch_bounds__(256) void cr_stats_kernel(const u16* __restrict__ Z,
                                                       const float* __restrict__ bias,
                                                       const int* __restrict__ lens,
                                                       const int* __restrict__ targets,
                                                       const int* __restrict__ tlens,
                                                       float* __restrict__ G,
                                                       float* __restrict__ klp) {
  int bp = blockIdx.x;   // 0..15
  int t = blockIdx.y;    // 0..999
  int tid = threadIdx.x;
  size_t r1 = (size_t)bp * Tlen + t;
  if (t >= lens[bp]) {               // dead block: G rows unread, KL masked
    if (tid == 0) klp[r1] = 0.0f;
    return;
  }
  int wave = tid >> 6, lane = tid & 63;
  size_t r2 = r1 + (size_t)16 * Tlen;
  const u16* z1 = Z + r1 * Vdim;
  const u16* z2 = Z + r2 * Vdim;

  __shared__ __attribute__((aligned(16))) float ls1[Vdim];
  __shared__ __attribute__((aligned(16))) float ls2[Vdim];
  __shared__ float red[8];

  const int c0 = tid * 8;            // this thread's 8 contiguous columns
  float v1[8], v2[8], e1[8], e2[8];
  float mx1 = NEG, mx2 = NEG;
  if (c0 < Vdim) {                   // tid < 250 (2000 = 250*8)
    short8 za = *(const short8*)&z1[c0];
    short8 zb = *(const short8*)&z2[c0];
    float4 b0 = *(const float4*)&bias[c0];
    float4 b1 = *(const float4*)&bias[c0 + 4];
    float bb[8] = {b0.x, b0.y, b0.z, b0.w, b1.x, b1.y, b1.z, b1.w};
    #pragma unroll
    for (int j = 0; j < 8; ++j) {
      v1[j] = bf2f((u16)za[j]) + bb[j];
      v2[j] = bf2f((u16)zb[j]) + bb[j];
      mx1 = fmaxf(mx1, v1[j]);
      mx2 = fmaxf(mx2, v2[j]);
    }
    *(float4*)&ls1[c0]     = (float4){v1[0], v1[1], v1[2], v1[3]};
    *(float4*)&ls1[c0 + 4] = (float4){v1[4], v1[5], v1[6], v1[7]};
    *(float4*)&ls2[c0]     = (float4){v2[0], v2[1], v2[2], v2[3]};
    *(float4*)&ls2[c0 + 4] = (float4){v2[4], v2[5], v2[6], v2[7]};
  } else {
    #pragma unroll
    for (int j = 0; j < 8; ++j) { v1[j] = NEG; v2[j] = NEG; }
  }
  float w1 = dppMax64(mx1), w2 = dppMax64(mx2);
  if (lane == 63) { red[wave] = w1; red[4 + wave] = w2; }
  __syncthreads();
  float M1 = fmaxf(fmaxf(red[0], red[1]), fmaxf(red[2], red[3]));
  float M2 = fmaxf(fmaxf(red[4], red[5]), fmaxf(red[6], red[7]));
  __syncthreads();
  float s1 = 0.0f, s2 = 0.0f;
  #pragma unroll
  for (int j = 0; j < 8; ++j) {
    e1[j] = expf(v1[j] - M1);   // 0 for padded cols (v = NEG)
    e2[j] = expf(v2[j] - M2);
    s1 += e1[j];
    s2 += e2[j];
  }
  s1 = dppSum64(s1); s2 = dppSum64(s2);
  if (lane == 63) { red[wave] = s1; red[4 + wave] = s2; }
  __syncthreads();
  float S1 = red[0] + red[1] + red[2] + red[3];
  float S2 = red[4] + red[5] + red[6] + red[7];
  float c1 = M1 + logf(S1);
  float c2 = M2 + logf(S2);
  float inv1 = 1.0f / S1;
  float inv2 = 1.0f / S2;

  if (tid < 64) {
    int i1 = min(2 * tid, Udim - 1);
    int i3 = min(2 * tid + 1, Udim - 1);
    int t1a = targets[bp * Udim + i1];
    int t1b = targets[bp * Udim + i3];
    int t2a = targets[(bp + 16) * Udim + i1];
    int t2b = targets[(bp + 16) * Udim + i3];
    int tl1 = tlens[bp];
    int tl2 = tlens[bp + 16];
    // LINEAR probabilities; labels past this sequence's target length -> 0
    // (keeps lattice states s > 2*tl exactly 0 in the scan).
    float4 g1 = {(2 * tid < tl1) ? expf(ls1[t1a] - c1) : 0.0f,
                 (2 * tid + 1 < tl1) ? expf(ls1[t1b] - c1) : 0.0f,
                 expf(ls1[0] - c1), 0.0f};
    float4 g2 = {(2 * tid < tl2) ? expf(ls2[t2a] - c2) : 0.0f,
                 (2 * tid + 1 < tl2) ? expf(ls2[t2b] - c2) : 0.0f,
                 expf(ls2[0] - c2), 0.0f};
    *(float4*)(G + r1 * GROW + 4 * tid) = g1;
    *(float4*)(G + r2 * GROW + 4 * tid) = g2;
  }

  float f = 0.0f;
  #pragma unroll
  for (int j = 0; j < 8; ++j) {
    // p = expf(v - c) == e * (1/S), exactly; padded cols: (0-0)*(NEG-NEG)=0.
    float p1 = e1[j] * inv1;
    float p2 = e2[j] * inv2;
    f += (p1 - p2) * (v1[j] - v2[j]);
  }
  __syncthreads();
  f = dppSum64(f);
  if (lane == 63) red[wave] = f;
  __syncthreads();
  if (tid == 0) {
    klp[r1] = red[0] + red[1] + red[2] + red[3];  // plain store, no atomic
  }
}

// ---------------- K4: CTC forward scan, one wave per sequence --------------
// LINEAR-space recurrence -- issue-count cuts (the kernel runs 1 wave/SIMD,
// so it is ISSUE-bound: every instruction ~2 cyc serial):
//  - 32-step superblock with two register banks (A/B) -> no s<-n copy movs
//  - skip conditions as float masks -> fma instead of cndmask+add
//  - rescale+kill every 8 steps: growth <= 3^8 ~ 2^12.7 off the 2^100 pin,
//    no overflow; flush headroom (~226 bits below max) intact
//  - no row clamp on prefetch: over-reads (< 48 KB past a 1 MB chunk) stay
//    inside the mapped workspace; values are discarded by tail freeze masks.
#define DECL3(p, i) float p##i##x, p##i##y, p##i##b;
#define LOADR(p, i, row) { float4 v = *(const float4*)(gb + (size_t)(row) * GROW + 4 * lane); \
    p##i##x = v.x; p##i##y = v.y; p##i##b = v.z; }

// unconditional step (main loop: every step here satisfies t < len)
#define COMPU(p, i) { \
    float pX = p##i##x, pY = p##i##y, pB = p##i##b; \
    float p3 = shiftup1(a3, 0.0f); \
    float t01 = a1 + a0; \
    float t23 = a3 + a2; \
    float n0 = (a0 + p3) * pB; \
    float n1 = fmaf(p3, fm1, t01) * pX; \
    float n2 = (a2 + a1) * pB; \
    float n3 = fmaf(a1, fm3, t23) * pY; \
    a0 = n0; a1 = n1; a2 = n2; a3 = n3; }

// guarded step (tail: freeze once past this sequence's input length)
#define COMPA(p, i, off) { \
    float pX = p##i##x, pY = p##i##y, pB = p##i##b; \
    float p3 = shiftup1(a3, 0.0f); \
    float t01 = a1 + a0; \
    float t23 = a3 + a2; \
    float n0 = (a0 + p3) * pB; \
    float n1 = fmaf(p3, fm1, t01) * pX; \
    float n2 = (a2 + a1) * pB; \
    float n3 = fmaf(a1, fm3, t23) * pY; \
    bool act = (t + (off)) < len; \
    a0 = act ? n0 : a0; a1 = act ? n1 : a1; \
    a2 = act ? n2 : a2; a3 = act ? n3 : a3; }

// DPP wave-max step: bound_ctrl=true fills invalid lanes with 0 (all a >= 0)
#define DPPMAX(m, ctrl) { int _r = __builtin_amdgcn_update_dpp(0,              \
      __float_as_int(m), ctrl, 0xF, 0xF, true);                               \
    m = fmaxf(m, __int_as_float(_r)); }

// Exact kill of states that cannot reach the readout, then exact power-of-2
// rescale pinning the wave max at ~2^100; logScale tracks the total scale.
#define RESCALE_KILL(tdone) {                                                 \
    int R = len - 1 - (tdone); R = R < 0 ? 0 : R;                             \
    int lo = end1 - 2 * R;                                                    \
    a0 = (base4 + 0 >= lo) ? a0 : 0.0f;                                       \
    a1 = (base4 + 1 >= lo) ? a1 : 0.0f;                                       \
    a2 = (base4 + 2 >= lo) ? a2 : 0.0f;                                       \
    a3 = (base4 + 3 >= lo) ? a3 : 0.0f;                                       \
    float m = fmaxf(fmaxf(a0, a1), fmaxf(a2, a3));                            \
    DPPMAX(m, 0x111) DPPMAX(m, 0x112) DPPMAX(m, 0x114) DPPMAX(m, 0x118)       \
    DPPMAX(m, 0x142) DPPMAX(m, 0x143)                                         \
    uint32_t mb = (uint32_t)__builtin_amdgcn_readlane(__float_as_int(m), 63); \
    int e = (int)((mb >> 23) & 0xffu);                                        \
    int sh = 227 - e;                                                         \
    sh = sh > 127 ? 127 : (sh < -126 ? -126 : sh);                            \
    float sc = __uint_as_float((uint32_t)(sh + 127) << 23);                   \
    a0 *= sc; a1 *= sc; a2 *= sc; a3 *= sc;                                   \
    logScale -= sh; }

__global__ __launch_bounds__(64, 1) void ctc_kernel(const float* __restrict__ G,
                                                    const int* __restrict__ targets,
                                                    const int* __restrict__ lens,
                                                    const int* __restrict__ tlens,
                                                    float* __restrict__ accum) {
  int b = blockIdx.x;
  int lane = threadIdx.x;
  const int* tgt = targets + b * Udim;
  int i1 = min(2 * lane, Udim - 1);
  int i3 = min(2 * lane + 1, Udim - 1);
  int l1 = tgt[i1];
  int l3 = tgt[i3];
  int lm1 = tgt[min(max(2 * lane - 1, 0), Udim - 1)];
  const float fm1 = ((lane >= 1) && (l1 != lm1)) ? 1.0f : 0.0f;  // skip1 mask
  const float fm3 = (l3 != l1) ? 1.0f : 0.0f;                    // skip3 mask
  int len = lens[b];
  int tl = tlens[b];
  const int end1 = 2 * tl - 1;       // readout states are end1 and end1+1
  const int base4 = 4 * lane;        // this lane owns states base4..base4+3
  const float* gb = G + (size_t)b * Tlen * GROW;

  // t=0 init (linear space): lane0's float4 = {p(tgt0), p(tgt1), blank, 0}
  float4 v0 = *(const float4*)(gb + 4 * lane);
  float a0 = (lane == 0) ? v0.z : 0.0f;
  float a1 = (lane == 0) ? v0.x : 0.0f;
  float a2 = 0.0f, a3 = 0.0f;
  int logScale = 0;

  DECL3(sA, 0)  DECL3(sA, 1)  DECL3(sA, 2)  DECL3(sA, 3)
  DECL3(sA, 4)  DECL3(sA, 5)  DECL3(sA, 6)  DECL3(sA, 7)
  DECL3(sA, 8)  DECL3(sA, 9)  DECL3(sA, 10) DECL3(sA, 11)
  DECL3(sA, 12) DECL3(sA, 13) DECL3(sA, 14) DECL3(sA, 15)
  DECL3(sB, 0)  DECL3(sB, 1)  DECL3(sB, 2)  DECL3(sB, 3)
  DECL3(sB, 4)  DECL3(sB, 5)  DECL3(sB, 6)  DECL3(sB, 7)
  DECL3(sB, 8)  DECL3(sB, 9)  DECL3(sB, 10) DECL3(sB, 11)
  DECL3(sB, 12) DECL3(sB, 13) DECL3(sB, 14) DECL3(sB, 15)

  // prime bank A with rows 1..16 (all valid: len >= 500)
  LOADR(sA, 0, 1)   LOADR(sA, 1, 2)   LOADR(sA, 2, 3)   LOADR(sA, 3, 4)
  LOADR(sA, 4, 5)   LOADR(sA, 5, 6)   LOADR(sA, 6, 7)   LOADR(sA, 7, 8)
  LOADR(sA, 8, 9)   LOADR(sA, 9, 10)  LOADR(sA, 10, 11) LOADR(sA, 11, 12)
  LOADR(sA, 12, 13) LOADR(sA, 13, 14) LOADR(sA, 14, 15) LOADR(sA, 15, 16)

  int steps = len - 1;               // recurrence covers t = 1 .. len-1
  int mainN = steps & ~31;           // floor to multiple of 32
  int t = 1;
  for (int blk = 0; blk < mainN; blk += 32) {
    // H0: refill bank B (rows t+16..t+31), consume bank A (steps t..t+15)
    LOADR(sB, 0, t + 16)  LOADR(sB, 1, t + 17)  LOADR(sB, 2, t + 18)  LOADR(sB, 3, t + 19)
    LOADR(sB, 4, t + 20)  LOADR(sB, 5, t + 21)  LOADR(sB, 6, t + 22)  LOADR(sB, 7, t + 23)
    LOADR(sB, 8, t + 24)  LOADR(sB, 9, t + 25)  LOADR(sB, 10, t + 26) LOADR(sB, 11, t + 27)
    LOADR(sB, 12, t + 28) LOADR(sB, 13, t + 29) LOADR(sB, 14, t + 30) LOADR(sB, 15, t + 31)
    __builtin_amdgcn_sched_barrier(0);
    COMPU(sA, 0)  COMPU(sA, 1)  COMPU(sA, 2)  COMPU(sA, 3)
    COMPU(sA, 4)  COMPU(sA, 5)  COMPU(sA, 6)  COMPU(sA, 7)
    RESCALE_KILL(t + 7)
    COMPU(sA, 8)  COMPU(sA, 9)  COMPU(sA, 10) COMPU(sA, 11)
    COMPU(sA, 12) COMPU(sA, 13) COMPU(sA, 14) COMPU(sA, 15)
    RESCALE_KILL(t + 15)
    // H1: refill bank A (rows t+32..t+47), consume bank B (steps t+16..t+31)
    LOADR(sA, 0, t + 32)  LOADR(sA, 1, t + 33)  LOADR(sA, 2, t + 34)  LOADR(sA, 3, t + 35)
    LOADR(sA, 4, t + 36)  LOADR(sA, 5, t + 37)  LOADR(sA, 6, t + 38)  LOADR(sA, 7, t + 39)
    LOADR(sA, 8, t + 40)  LOADR(sA, 9, t + 41)  LOADR(sA, 10, t + 42) LOADR(sA, 11, t + 43)
    LOADR(sA, 12, t + 44) LOADR(sA, 13, t + 45) LOADR(sA, 14, t + 46) LOADR(sA, 15, t + 47)
    __builtin_amdgcn_sched_barrier(0);
    COMPU(sB, 0)  COMPU(sB, 1)  COMPU(sB, 2)  COMPU(sB, 3)
    COMPU(sB, 4)  COMPU(sB, 5)  COMPU(sB, 6)  COMPU(sB, 7)
    RESCALE_KILL(t + 23)
    COMPU(sB, 8)  COMPU(sB, 9)  COMPU(sB, 10) COMPU(sB, 11)
    COMPU(sB, 12) COMPU(sB, 13) COMPU(sB, 14) COMPU(sB, 15)
    RESCALE_KILL(t + 31)
    t += 32;
  }
  {
    // tail: up to 32 guarded steps. Bank A holds rows t..t+15 (loaded by the
    // last H1); refill bank B for rows t+16..t+31 (over-reads are garbage,
    // discarded by the freeze masks).
    LOADR(sB, 0, t + 16)  LOADR(sB, 1, t + 17)  LOADR(sB, 2, t + 18)  LOADR(sB, 3, t + 19)
    LOADR(sB, 4, t + 20)  LOADR(sB, 5, t + 21)  LOADR(sB, 6, t + 22)  LOADR(sB, 7, t + 23)
    LOADR(sB, 8, t + 24)  LOADR(sB, 9, t + 25)  LOADR(sB, 10, t + 26) LOADR(sB, 11, t + 27)
    LOADR(sB, 12, t + 28) LOADR(sB, 13, t + 29) LOADR(sB, 14, t + 30) LOADR(sB, 15, t + 31)
    __builtin_amdgcn_sched_barrier(0);
    COMPA(sA, 0, 0)   COMPA(sA, 1, 1)   COMPA(sA, 2, 2)   COMPA(sA, 3, 3)
    COMPA(sA, 4, 4)   COMPA(sA, 5, 5)   COMPA(sA, 6, 6)   COMPA(sA, 7, 7)
    RESCALE_KILL(t + 7)
    COMPA(sA, 8, 8)   COMPA(sA, 9, 9)   COMPA(sA, 10, 10) COMPA(sA, 11, 11)
    COMPA(sA, 12, 12) COMPA(sA, 13, 13) COMPA(sA, 14, 14) COMPA(sA, 15, 15)
    RESCALE_KILL(t + 15)
    COMPA(sB, 0, 16)  COMPA(sB, 1, 17)  COMPA(sB, 2, 18)  COMPA(sB, 3, 19)
    COMPA(sB, 4, 20)  COMPA(sB, 5, 21)  COMPA(sB, 6, 22)  COMPA(sB, 7, 23)
    RESCALE_KILL(t + 23)
    COMPA(sB, 8, 24)  COMPA(sB, 9, 25)  COMPA(sB, 10, 26) COMPA(sB, 11, 27)
    COMPA(sB, 12, 28) COMPA(sB, 13, 29) COMPA(sB, 14, 30) COMPA(sB, 15, 31)
    RESCALE_KILL(t + 31)
  }

  __shared__ float fin[256];
  fin[4 * lane + 0] = a0;
  fin[4 * lane + 1] = a1;
  fin[4 * lane + 2] = a2;
  fin[4 * lane + 3] = a3;
  __syncthreads();
  if (lane == 0) {
    int end = 2 * tl;
    float sum = fin[end] + fin[end - 1];
    float loss = -LN2 * (log2f(sum) + (float)logScale);
    atomicAdd(&accum[0], 0.5f * loss);
  }
}

// ---------------- K5: finalize -- KL partial reduction + FP32 output -------
// Sums the 16000 per-block KL partials (uncontended stores from cr_stats)
// in one 1024-thread block: 16 coalesced loads/thread, DPP wave reduce,
// LDS combine. Replaces ~12000 serialized same-address atomics (~14 ns each
// = the old 166 us cr_stats floor).
__global__ __launch_bounds__(1024) void finalize_kernel(const float* __restrict__ accum,
                                                        const float* __restrict__ klp,
                                                        float* __restrict__ out) {
  __shared__ float red[16];
  int tid = threadIdx.x;
  float s = 0.0f;
  for (int i = tid; i < 16 * Tlen; i += 1024) s += klp[i];
  s = dppSum64(s);
  int wave = tid >> 6, lane = tid & 63;
  if (lane == 63) red[wave] = s;
  __syncthreads();
  if (tid == 0) {
    float tot = 0.0f;
    #pragma unroll
    for (int w = 0; w < 16; ++w) tot += red[w];
    out[0] = accum[0];
    out[1] = 0.5f * tot;
  }
}

extern "C" void kernel_launch(void* const* d_in, const int* in_sizes, int n_in,
                              void* d_out, int out_size, void* d_ws, size_t ws_size,
                              hipStream_t stream) {
  const float* enc = (const float*)d_in[0];
  const float* W = (const float*)d_in[1];
  const float* bias = (const float*)d_in[2];
  const int* lens = (const int*)d_in[3];
  const int* targets = (const int*)d_in[4];
  const int* tlens = (const int*)d_in[5];

  char* ws = (char*)d_ws;
  u16* a_bf = (u16*)(ws + WS_ABF);
  u16* w_bf = (u16*)(ws + WS_WBF);
  u16* Zb   = (u16*)(ws + WS_Z);
  float* Gp  = (float*)(ws + WS_G);   // aliases a_bf (dead after gemm)
  float* klp = (float*)(ws + WS_KL);  // aliases w_bf (dead after gemm)
  float* accum = (float*)(ws + WS_ACC);

  hipLaunchKernelGGL(convert_kernel, dim3(1024), dim3(256), 0, stream,
                     (const float4*)enc, (const float4*)W, (uint4*)a_bf, (uint4*)w_bf, accum);
  hipLaunchKernelGGL(gemm_kernel, dim3(16, 250), dim3(256), 0, stream,
                     a_bf, w_bf, Zb);
  hipLaunchKernelGGL(cr_stats_kernel, dim3(16, 1000), dim3(256), 0, stream,
                     Zb, bias, lens, targets, tlens, Gp, klp);
  hipLaunchKernelGGL(ctc_kernel, dim3(Bsz), dim3(64), 0, stream,
                     Gp, targets, lens, tlens, accum);
  hipLaunchKernelGGL(finalize_kernel, dim3(1), dim3(1024), 0, stream,
                     accum, klp, (float*)d_out);
}

// Round 7
// 289.743 us; speedup vs baseline: 2.0486x; 1.0565x over previous
//
#include <hip/hip_runtime.h>
#include <hip/hip_bf16.h>
#include <cstdint>

#define NEG (-1.0e30f)
#define INVLN2 1.44269504088896340736f
#define LN2    0.69314718055994530942f

typedef unsigned short u16;
typedef __attribute__((ext_vector_type(8))) short short8;
typedef __attribute__((ext_vector_type(4))) float f32x4;

typedef const __attribute__((address_space(1))) void cg_void;
typedef __attribute__((address_space(3))) void lds_void;

// dims
#define Bsz   32
#define Tlen  1000
#define Cdim  512
#define Vdim  2000
#define Udim  100
#define Mrows (Bsz * Tlen)   // 32000
#define Npad  2048
#define GROW  256            // G row stride in floats (1024 B): lane i owns
                             // float4 {p(tgt[2i]), p(tgt[2i+1]), p(blank), 0} (LINEAR probs)

// ws layout (bytes). G (32.768 MB) aliases a_bf exactly (dead after gemm).
// klp (64 KB, KL per-block partials) aliases w_bf (dead after gemm).
#define WS_ABF 0u
#define WS_G   0u
#define WS_WBF 32768000u                    // a_bf/G: 32000*1024
#define WS_KL  WS_WBF                       // 16*1000 floats, aliases w_bf
#define WS_Z   (WS_WBF + 2097152u)          // w_bf: 2048*512*2
#define WS_ACC (WS_Z + 128000000u)          // Z: 32000*2000*2; then accum: 2 floats

__device__ inline u16 f2bf(float x) {
  uint32_t u = __float_as_uint(x);
  uint32_t r = (u + 0x7fffu + ((u >> 16) & 1u)) >> 16;
  return (u16)r;
}
__device__ inline float bf2f(u16 u) {
  return __uint_as_float(((uint32_t)u) << 16);
}

// ---- DPP wave64 reductions (pure VALU, no LDS). Result valid in lane 63. ----
// ctrl operand of update_dpp must be a literal constant -> per-stage macros.
#define DPP_MAX_STAGE(m, ctrl) { \
    int _r = __builtin_amdgcn_update_dpp(__float_as_int(m), __float_as_int(m), \
                                         ctrl, 0xF, 0xF, false); \
    m = fmaxf(m, __int_as_float(_r)); }
#define DPP_SUM_STAGE(v, ctrl) { \
    int _r = __builtin_amdgcn_update_dpp(0, __float_as_int(v), \
                                         ctrl, 0xF, 0xF, true); \
    v += __int_as_float(_r); }

__device__ inline float dppMax64(float m) {
  DPP_MAX_STAGE(m, 0x111) DPP_MAX_STAGE(m, 0x112) DPP_MAX_STAGE(m, 0x114)
  DPP_MAX_STAGE(m, 0x118) DPP_MAX_STAGE(m, 0x142) DPP_MAX_STAGE(m, 0x143)
  return m;  // valid in lane 63
}
__device__ inline float dppSum64(float v) {
  DPP_SUM_STAGE(v, 0x111) DPP_SUM_STAGE(v, 0x112) DPP_SUM_STAGE(v, 0x114)
  DPP_SUM_STAGE(v, 0x118) DPP_SUM_STAGE(v, 0x142) DPP_SUM_STAGE(v, 0x143)
  return v;  // valid in lane 63
}

// shift value from lane-1 into this lane via DPP wave_shr:1 (VALU, no LDS).
__device__ inline float shiftup1(float x, float fill) {
  int r = __builtin_amdgcn_update_dpp(__float_as_int(fill), __float_as_int(x),
                                      0x138, 0xF, 0xF, false);
  return __int_as_float(r);
}

// ---------------- K1: fp32 -> bf16 conversion, vectorized ------------------
// Round-7: rows with t >= lens[b] are skipped (their Z output is never read;
// garbage bf16 in dead a_bf rows only propagates to dead Z rows).
__global__ void convert_kernel(const float4* __restrict__ enc4, const float4* __restrict__ W4,
                               uint4* __restrict__ a4, uint4* __restrict__ w4,
                               const int* __restrict__ lens,
                               float* __restrict__ accum) {
  int idx = blockIdx.x * blockDim.x + threadIdx.x;
  int stride = gridDim.x * blockDim.x;
  if (idx == 0) { accum[0] = 0.0f; accum[1] = 0.0f; }
  const int nA = Mrows * Cdim / 8;
  const int nW = Vdim * Cdim / 8;
  const int nWp = Npad * Cdim / 8;
  for (int i = idx; i < nA; i += stride) {
    int row = i >> 6;                 // 64 groups of 8 per 512-col row
    int b = row / 1000;
    int t = row - b * 1000;
    if (t >= lens[b]) continue;       // dead row: Z never read
    float4 x = enc4[2 * i], y = enc4[2 * i + 1];
    uint4 o;
    o.x = (uint32_t)f2bf(x.x) | ((uint32_t)f2bf(x.y) << 16);
    o.y = (uint32_t)f2bf(x.z) | ((uint32_t)f2bf(x.w) << 16);
    o.z = (uint32_t)f2bf(y.x) | ((uint32_t)f2bf(y.y) << 16);
    o.w = (uint32_t)f2bf(y.z) | ((uint32_t)f2bf(y.w) << 16);
    a4[i] = o;
  }
  for (int i = idx; i < nWp; i += stride) {
    uint4 o = {0, 0, 0, 0};
    if (i < nW) {
      float4 x = W4[2 * i], y = W4[2 * i + 1];
      o.x = (uint32_t)f2bf(x.x) | ((uint32_t)f2bf(x.y) << 16);
      o.y = (uint32_t)f2bf(x.z) | ((uint32_t)f2bf(x.w) << 16);
      o.z = (uint32_t)f2bf(y.x) | ((uint32_t)f2bf(y.y) << 16);
      o.w = (uint32_t)f2bf(y.z) | ((uint32_t)f2bf(y.w) << 16);
    }
    w4[i] = o;
  }
}

// ---------------- K2: bf16 GEMM (A: 32000x512, W: 2048x512, C = A*W^T) -----
// Round-7: (1) XCD-grouping swizzle -- 1D grid 4000; chunk of 128 ids = 8
// m-tiles x 16 n-tiles with mTile = chunk*8 + id%8, so the 16 blocks sharing
// an A-tile are all congruent mod 8 (same XCD round-robin slot) within a
// concurrent 128-id window: A-tile filled into ONE L2 instead of 8 (r6
// counters: FETCH 132 MB vs ~35 MB ideal = 4x A over-fetch). (2) dead-tile
// early exit: tile fully dead iff it doesn't cross a sequence boundary
// (t0 <= 872) and t0 >= lens[b] -- ~24% of blocks (their Z rows are never
// read; cr_stats early-exits those t).
__global__ __launch_bounds__(256) void gemm_kernel(const u16* __restrict__ A,
                                                   const u16* __restrict__ Wb,
                                                   const int* __restrict__ lens,
                                                   u16* __restrict__ Z) {
  const int id = blockIdx.x;
  const int c = id >> 7, r = id & 127;
  int mTile, nTile;
  if (c < 31) { mTile = c * 8 + (r & 7); nTile = r >> 3; }
  else        { mTile = 248 + (r & 1);   nTile = r >> 1; }   // tail: 2 m-tiles
  const int mBase = mTile * 128;
  const int nBase = nTile * 128;
  {
    int bSeq = mBase / 1000;
    int t0 = mBase - bSeq * 1000;
    if (t0 <= 872 && t0 >= lens[bSeq]) return;   // whole tile dead
  }

  __shared__ __attribute__((aligned(16))) u16 As[128 * 64];
  __shared__ __attribute__((aligned(16))) u16 Bs[128 * 64];
  const int tid = threadIdx.x;
  const int wave = tid >> 6;
  const int lane = tid & 63;
  const int m_lane = lane & 15;
  const int quad = lane >> 4;

  f32x4 acc[4][4];
  const f32x4 zero4 = {0.0f, 0.0f, 0.0f, 0.0f};
  #pragma unroll
  for (int i = 0; i < 4; ++i)
    #pragma unroll
    for (int j = 0; j < 4; ++j) acc[i][j] = zero4;

  for (int k0 = 0; k0 < Cdim; k0 += 64) {
    #pragma unroll
    for (int rr = 0; rr < 4; ++rr) {
      int u = rr * 256 + tid;
      int g = u >> 3;
      int q = (u & 7) ^ (g & 7);
      const u16* gpA = A + ((size_t)(mBase + g) << 9) + (k0 + (q << 3));
      __builtin_amdgcn_global_load_lds((cg_void*)gpA, (lds_void*)&As[(rr * 4 + wave) * 512],
                                       16, 0, 0);
      const u16* gpB = Wb + ((size_t)(nBase + g) << 9) + (k0 + (q << 3));
      __builtin_amdgcn_global_load_lds((cg_void*)gpB, (lds_void*)&Bs[(rr * 4 + wave) * 512],
                                       16, 0, 0);
    }
    __syncthreads();
    #pragma unroll
    for (int kk = 0; kk < 2; ++kk) {
      short8 af[4], bfv[4];
      #pragma unroll
      for (int mi = 0; mi < 4; ++mi) {
        int row = (wave >> 1) * 64 + mi * 16 + m_lane;
        int q = (kk * 4 + quad) ^ (row & 7);
        af[mi] = *(const short8*)&As[row * 64 + (q << 3)];
      }
      #pragma unroll
      for (int ni = 0; ni < 4; ++ni) {
        int col = (wave & 1) * 64 + ni * 16 + m_lane;
        int q = (kk * 4 + quad) ^ (col & 7);
        bfv[ni] = *(const short8*)&Bs[col * 64 + (q << 3)];
      }
      #pragma unroll
      for (int mi = 0; mi < 4; ++mi)
        #pragma unroll
        for (int ni = 0; ni < 4; ++ni)
          acc[mi][ni] = __builtin_amdgcn_mfma_f32_16x16x32_bf16(af[mi], bfv[ni],
                                                                acc[mi][ni], 0, 0, 0);
    }
    __syncthreads();
  }
  #pragma unroll
  for (int ni = 0; ni < 4; ++ni) {
    int col = nBase + (wave & 1) * 64 + ni * 16 + m_lane;
    if (col < Vdim) {
      #pragma unroll
      for (int mi = 0; mi < 4; ++mi) {
        int row0 = mBase + (wave >> 1) * 64 + mi * 16 + quad * 4;
        #pragma unroll
        for (int rg = 0; rg < 4; ++rg)
          Z[(size_t)(row0 + rg) * Vdim + col] = f2bf(acc[mi][ni][rg]);
      }
    }
  }
}

// ---------------- K3: fused softmax stats + CR loss + CTC gather -----------
// Per-block KL partial -> klp (uncontended store; the r5 atomicAdd stream was
// a 166 us serialization floor). Z/bias loads vectorized (short8 + float4).
__global__ __launch_bounds__(256) void cr_stats_kernel(const u16* __restrict__ Z,
                                                       const float* __restrict__ bias,
                                                       const int* __restrict__ lens,
                                                       const int* __restrict__ targets,
                                                       const int* __restrict__ tlens,
                                                       float* __restrict__ G,
                                                       float* __restrict__ klp) {
  int bp = blockIdx.x;   // 0..15
  int t = blockIdx.y;    // 0..999
  int tid = threadIdx.x;
  size_t r1 = (size_t)bp * Tlen + t;
  if (t >= lens[bp]) {               // dead block: G rows unread, KL masked
    if (tid == 0) klp[r1] = 0.0f;
    return;
  }
  int wave = tid >> 6, lane = tid & 63;
  size_t r2 = r1 + (size_t)16 * Tlen;
  const u16* z1 = Z + r1 * Vdim;
  const u16* z2 = Z + r2 * Vdim;

  __shared__ __attribute__((aligned(16))) float ls1[Vdim];
  __shared__ __attribute__((aligned(16))) float ls2[Vdim];
  __shared__ float red[8];

  const int c0 = tid * 8;            // this thread's 8 contiguous columns
  float v1[8], v2[8], e1[8], e2[8];
  float mx1 = NEG, mx2 = NEG;
  if (c0 < Vdim) {                   // tid < 250 (2000 = 250*8)
    short8 za = *(const short8*)&z1[c0];
    short8 zb = *(const short8*)&z2[c0];
    float4 b0 = *(const float4*)&bias[c0];
    float4 b1 = *(const float4*)&bias[c0 + 4];
    float bb[8] = {b0.x, b0.y, b0.z, b0.w, b1.x, b1.y, b1.z, b1.w};
    #pragma unroll
    for (int j = 0; j < 8; ++j) {
      v1[j] = bf2f((u16)za[j]) + bb[j];
      v2[j] = bf2f((u16)zb[j]) + bb[j];
      mx1 = fmaxf(mx1, v1[j]);
      mx2 = fmaxf(mx2, v2[j]);
    }
    *(float4*)&ls1[c0]     = (float4){v1[0], v1[1], v1[2], v1[3]};
    *(float4*)&ls1[c0 + 4] = (float4){v1[4], v1[5], v1[6], v1[7]};
    *(float4*)&ls2[c0]     = (float4){v2[0], v2[1], v2[2], v2[3]};
    *(float4*)&ls2[c0 + 4] = (float4){v2[4], v2[5], v2[6], v2[7]};
  } else {
    #pragma unroll
    for (int j = 0; j < 8; ++j) { v1[j] = NEG; v2[j] = NEG; }
  }
  float w1 = dppMax64(mx1), w2 = dppMax64(mx2);
  if (lane == 63) { red[wave] = w1; red[4 + wave] = w2; }
  __syncthreads();
  float M1 = fmaxf(fmaxf(red[0], red[1]), fmaxf(red[2], red[3]));
  float M2 = fmaxf(fmaxf(red[4], red[5]), fmaxf(red[6], red[7]));
  __syncthreads();
  float s1 = 0.0f, s2 = 0.0f;
  #pragma unroll
  for (int j = 0; j < 8; ++j) {
    e1[j] = expf(v1[j] - M1);   // 0 for padded cols (v = NEG)
    e2[j] = expf(v2[j] - M2);
    s1 += e1[j];
    s2 += e2[j];
  }
  s1 = dppSum64(s1); s2 = dppSum64(s2);
  if (lane == 63) { red[wave] = s1; red[4 + wave] = s2; }
  __syncthreads();
  float S1 = red[0] + red[1] + red[2] + red[3];
  float S2 = red[4] + red[5] + red[6] + red[7];
  float c1 = M1 + logf(S1);
  float c2 = M2 + logf(S2);
  float inv1 = 1.0f / S1;
  float inv2 = 1.0f / S2;

  if (tid < 64) {
    int i1 = min(2 * tid, Udim - 1);
    int i3 = min(2 * tid + 1, Udim - 1);
    int t1a = targets[bp * Udim + i1];
    int t1b = targets[bp * Udim + i3];
    int t2a = targets[(bp + 16) * Udim + i1];
    int t2b = targets[(bp + 16) * Udim + i3];
    int tl1 = tlens[bp];
    int tl2 = tlens[bp + 16];
    // LINEAR probabilities; labels past this sequence's target length -> 0
    // (keeps lattice states s > 2*tl exactly 0 in the scan).
    float4 g1 = {(2 * tid < tl1) ? expf(ls1[t1a] - c1) : 0.0f,
                 (2 * tid + 1 < tl1) ? expf(ls1[t1b] - c1) : 0.0f,
                 expf(ls1[0] - c1), 0.0f};
    float4 g2 = {(2 * tid < tl2) ? expf(ls2[t2a] - c2) : 0.0f,
                 (2 * tid + 1 < tl2) ? expf(ls2[t2b] - c2) : 0.0f,
                 expf(ls2[0] - c2), 0.0f};
    *(float4*)(G + r1 * GROW + 4 * tid) = g1;
    *(float4*)(G + r2 * GROW + 4 * tid) = g2;
  }

  float f = 0.0f;
  #pragma unroll
  for (int j = 0; j < 8; ++j) {
    // p = expf(v - c) == e * (1/S), exactly; padded cols: (0-0)*(NEG-NEG)=0.
    float p1 = e1[j] * inv1;
    float p2 = e2[j] * inv2;
    f += (p1 - p2) * (v1[j] - v2[j]);
  }
  __syncthreads();
  f = dppSum64(f);
  if (lane == 63) red[wave] = f;
  __syncthreads();
  if (tid == 0) {
    klp[r1] = red[0] + red[1] + red[2] + red[3];  // plain store, no atomic
  }
}

// ---------------- K4: CTC forward scan, one wave per sequence --------------
// LINEAR-space recurrence -- issue-count cuts (the kernel runs 1 wave/SIMD,
// so it is ISSUE-bound: every instruction ~2 cyc serial):
//  - 32-step superblock with two register banks (A/B) -> no s<-n copy movs
//  - skip conditions as float masks -> fma instead of cndmask+add
//  - rescale+kill every 8 steps: growth <= 3^8 ~ 2^12.7 off the 2^100 pin,
//    no overflow; flush headroom (~226 bits below max) intact
//  - no row clamp on prefetch: over-reads (< 48 KB past a 1 MB chunk) stay
//    inside the mapped workspace; values are discarded by tail freeze masks.
#define DECL3(p, i) float p##i##x, p##i##y, p##i##b;
#define LOADR(p, i, row) { float4 v = *(const float4*)(gb + (size_t)(row) * GROW + 4 * lane); \
    p##i##x = v.x; p##i##y = v.y; p##i##b = v.z; }

// unconditional step (main loop: every step here satisfies t < len)
#define COMPU(p, i) { \
    float pX = p##i##x, pY = p##i##y, pB = p##i##b; \
    float p3 = shiftup1(a3, 0.0f); \
    float t01 = a1 + a0; \
    float t23 = a3 + a2; \
    float n0 = (a0 + p3) * pB; \
    float n1 = fmaf(p3, fm1, t01) * pX; \
    float n2 = (a2 + a1) * pB; \
    float n3 = fmaf(a1, fm3, t23) * pY; \
    a0 = n0; a1 = n1; a2 = n2; a3 = n3; }

// guarded step (tail: freeze once past this sequence's input length)
#define COMPA(p, i, off) { \
    float pX = p##i##x, pY = p##i##y, pB = p##i##b; \
    float p3 = shiftup1(a3, 0.0f); \
    float t01 = a1 + a0; \
    float t23 = a3 + a2; \
    float n0 = (a0 + p3) * pB; \
    float n1 = fmaf(p3, fm1, t01) * pX; \
    float n2 = (a2 + a1) * pB; \
    float n3 = fmaf(a1, fm3, t23) * pY; \
    bool act = (t + (off)) < len; \
    a0 = act ? n0 : a0; a1 = act ? n1 : a1; \
    a2 = act ? n2 : a2; a3 = act ? n3 : a3; }

// DPP wave-max step: bound_ctrl=true fills invalid lanes with 0 (all a >= 0)
#define DPPMAX(m, ctrl) { int _r = __builtin_amdgcn_update_dpp(0,              \
      __float_as_int(m), ctrl, 0xF, 0xF, true);                               \
    m = fmaxf(m, __int_as_float(_r)); }

// Exact kill of states that cannot reach the readout, then exact power-of-2
// rescale pinning the wave max at ~2^100; logScale tracks the total scale.
#define RESCALE_KILL(tdone) {                                                 \
    int R = len - 1 - (tdone); R = R < 0 ? 0 : R;                             \
    int lo = end1 - 2 * R;                                                    \
    a0 = (base4 + 0 >= lo) ? a0 : 0.0f;                                       \
    a1 = (base4 + 1 >= lo) ? a1 : 0.0f;                                       \
    a2 = (base4 + 2 >= lo) ? a2 : 0.0f;                                       \
    a3 = (base4 + 3 >= lo) ? a3 : 0.0f;                                       \
    float m = fmaxf(fmaxf(a0, a1), fmaxf(a2, a3));                            \
    DPPMAX(m, 0x111) DPPMAX(m, 0x112) DPPMAX(m, 0x114) DPPMAX(m, 0x118)       \
    DPPMAX(m, 0x142) DPPMAX(m, 0x143)                                         \
    uint32_t mb = (uint32_t)__builtin_amdgcn_readlane(__float_as_int(m), 63); \
    int e = (int)((mb >> 23) & 0xffu);                                        \
    int sh = 227 - e;                                                         \
    sh = sh > 127 ? 127 : (sh < -126 ? -126 : sh);                            \
    float sc = __uint_as_float((uint32_t)(sh + 127) << 23);                   \
    a0 *= sc; a1 *= sc; a2 *= sc; a3 *= sc;                                   \
    logScale -= sh; }

__global__ __launch_bounds__(64, 1) void ctc_kernel(const float* __restrict__ G,
                                                    const int* __restrict__ targets,
                                                    const int* __restrict__ lens,
                                                    const int* __restrict__ tlens,
                                                    float* __restrict__ accum) {
  int b = blockIdx.x;
  int lane = threadIdx.x;
  const int* tgt = targets + b * Udim;
  int i1 = min(2 * lane, Udim - 1);
  int i3 = min(2 * lane + 1, Udim - 1);
  int l1 = tgt[i1];
  int l3 = tgt[i3];
  int lm1 = tgt[min(max(2 * lane - 1, 0), Udim - 1)];
  const float fm1 = ((lane >= 1) && (l1 != lm1)) ? 1.0f : 0.0f;  // skip1 mask
  const float fm3 = (l3 != l1) ? 1.0f : 0.0f;                    // skip3 mask
  int len = lens[b];
  int tl = tlens[b];
  const int end1 = 2 * tl - 1;       // readout states are end1 and end1+1
  const int base4 = 4 * lane;        // this lane owns states base4..base4+3
  const float* gb = G + (size_t)b * Tlen * GROW;

  // t=0 init (linear space): lane0's float4 = {p(tgt0), p(tgt1), blank, 0}
  float4 v0 = *(const float4*)(gb + 4 * lane);
  float a0 = (lane == 0) ? v0.z : 0.0f;
  float a1 = (lane == 0) ? v0.x : 0.0f;
  float a2 = 0.0f, a3 = 0.0f;
  int logScale = 0;

  DECL3(sA, 0)  DECL3(sA, 1)  DECL3(sA, 2)  DECL3(sA, 3)
  DECL3(sA, 4)  DECL3(sA, 5)  DECL3(sA, 6)  DECL3(sA, 7)
  DECL3(sA, 8)  DECL3(sA, 9)  DECL3(sA, 10) DECL3(sA, 11)
  DECL3(sA, 12) DECL3(sA, 13) DECL3(sA, 14) DECL3(sA, 15)
  DECL3(sB, 0)  DECL3(sB, 1)  DECL3(sB, 2)  DECL3(sB, 3)
  DECL3(sB, 4)  DECL3(sB, 5)  DECL3(sB, 6)  DECL3(sB, 7)
  DECL3(sB, 8)  DECL3(sB, 9)  DECL3(sB, 10) DECL3(sB, 11)
  DECL3(sB, 12) DECL3(sB, 13) DECL3(sB, 14) DECL3(sB, 15)

  // prime bank A with rows 1..16 (all valid: len >= 500)
  LOADR(sA, 0, 1)   LOADR(sA, 1, 2)   LOADR(sA, 2, 3)   LOADR(sA, 3, 4)
  LOADR(sA, 4, 5)   LOADR(sA, 5, 6)   LOADR(sA, 6, 7)   LOADR(sA, 7, 8)
  LOADR(sA, 8, 9)   LOADR(sA, 9, 10)  LOADR(sA, 10, 11) LOADR(sA, 11, 12)
  LOADR(sA, 12, 13) LOADR(sA, 13, 14) LOADR(sA, 14, 15) LOADR(sA, 15, 16)

  int steps = len - 1;               // recurrence covers t = 1 .. len-1
  int mainN = steps & ~31;           // floor to multiple of 32
  int t = 1;
  for (int blk = 0; blk < mainN; blk += 32) {
    // H0: refill bank B (rows t+16..t+31), consume bank A (steps t..t+15)
    LOADR(sB, 0, t + 16)  LOADR(sB, 1, t + 17)  LOADR(sB, 2, t + 18)  LOADR(sB, 3, t + 19)
    LOADR(sB, 4, t + 20)  LOADR(sB, 5, t + 21)  LOADR(sB, 6, t + 22)  LOADR(sB, 7, t + 23)
    LOADR(sB, 8, t + 24)  LOADR(sB, 9, t + 25)  LOADR(sB, 10, t + 26) LOADR(sB, 11, t + 27)
    LOADR(sB, 12, t + 28) LOADR(sB, 13, t + 29) LOADR(sB, 14, t + 30) LOADR(sB, 15, t + 31)
    __builtin_amdgcn_sched_barrier(0);
    COMPU(sA, 0)  COMPU(sA, 1)  COMPU(sA, 2)  COMPU(sA, 3)
    COMPU(sA, 4)  COMPU(sA, 5)  COMPU(sA, 6)  COMPU(sA, 7)
    RESCALE_KILL(t + 7)
    COMPU(sA, 8)  COMPU(sA, 9)  COMPU(sA, 10) COMPU(sA, 11)
    COMPU(sA, 12) COMPU(sA, 13) COMPU(sA, 14) COMPU(sA, 15)
    RESCALE_KILL(t + 15)
    // H1: refill bank A (rows t+32..t+47), consume bank B (steps t+16..t+31)
    LOADR(sA, 0, t + 32)  LOADR(sA, 1, t + 33)  LOADR(sA, 2, t + 34)  LOADR(sA, 3, t + 35)
    LOADR(sA, 4, t + 36)  LOADR(sA, 5, t + 37)  LOADR(sA, 6, t + 38)  LOADR(sA, 7, t + 39)
    LOADR(sA, 8, t + 40)  LOADR(sA, 9, t + 41)  LOADR(sA, 10, t + 42) LOADR(sA, 11, t + 43)
    LOADR(sA, 12, t + 44) LOADR(sA, 13, t + 45) LOADR(sA, 14, t + 46) LOADR(sA, 15, t + 47)
    __builtin_amdgcn_sched_barrier(0);
    COMPU(sB, 0)  COMPU(sB, 1)  COMPU(sB, 2)  COMPU(sB, 3)
    COMPU(sB, 4)  COMPU(sB, 5)  COMPU(sB, 6)  COMPU(sB, 7)
    RESCALE_KILL(t + 23)
    COMPU(sB, 8)  COMPU(sB, 9)  COMPU(sB, 10) COMPU(sB, 11)
    COMPU(sB, 12) COMPU(sB, 13) COMPU(sB, 14) COMPU(sB, 15)
    RESCALE_KILL(t + 31)
    t += 32;
  }
  {
    // tail: up to 32 guarded steps. Bank A holds rows t..t+15 (loaded by the
    // last H1); refill bank B for rows t+16..t+31 (over-reads are garbage,
    // discarded by the freeze masks).
    LOADR(sB, 0, t + 16)  LOADR(sB, 1, t + 17)  LOADR(sB, 2, t + 18)  LOADR(sB, 3, t + 19)
    LOADR(sB, 4, t + 20)  LOADR(sB, 5, t + 21)  LOADR(sB, 6, t + 22)  LOADR(sB, 7, t + 23)
    LOADR(sB, 8, t + 24)  LOADR(sB, 9, t + 25)  LOADR(sB, 10, t + 26) LOADR(sB, 11, t + 27)
    LOADR(sB, 12, t + 28) LOADR(sB, 13, t + 29) LOADR(sB, 14, t + 30) LOADR(sB, 15, t + 31)
    __builtin_amdgcn_sched_barrier(0);
    COMPA(sA, 0, 0)   COMPA(sA, 1, 1)   COMPA(sA, 2, 2)   COMPA(sA, 3, 3)
    COMPA(sA, 4, 4)   COMPA(sA, 5, 5)   COMPA(sA, 6, 6)   COMPA(sA, 7, 7)
    RESCALE_KILL(t + 7)
    COMPA(sA, 8, 8)   COMPA(sA, 9, 9)   COMPA(sA, 10, 10) COMPA(sA, 11, 11)
    COMPA(sA, 12, 12) COMPA(sA, 13, 13) COMPA(sA, 14, 14) COMPA(sA, 15, 15)
    RESCALE_KILL(t + 15)
    COMPA(sB, 0, 16)  COMPA(sB, 1, 17)  COMPA(sB, 2, 18)  COMPA(sB, 3, 19)
    COMPA(sB, 4, 20)  COMPA(sB, 5, 21)  COMPA(sB, 6, 22)  COMPA(sB, 7, 23)
    RESCALE_KILL(t + 23)
    COMPA(sB, 8, 24)  COMPA(sB, 9, 25)  COMPA(sB, 10, 26) COMPA(sB, 11, 27)
    COMPA(sB, 12, 28) COMPA(sB, 13, 29) COMPA(sB, 14, 30) COMPA(sB, 15, 31)
    RESCALE_KILL(t + 31)
  }

  __shared__ float fin[256];
  fin[4 * lane + 0] = a0;
  fin[4 * lane + 1] = a1;
  fin[4 * lane + 2] = a2;
  fin[4 * lane + 3] = a3;
  __syncthreads();
  if (lane == 0) {
    int end = 2 * tl;
    float sum = fin[end] + fin[end - 1];
    float loss = -LN2 * (log2f(sum) + (float)logScale);
    atomicAdd(&accum[0], 0.5f * loss);
  }
}

// ---------------- K5: finalize -- KL partial reduction + FP32 output -------
__global__ __launch_bounds__(1024) void finalize_kernel(const float* __restrict__ accum,
                                                        const float* __restrict__ klp,
                                                        float* __restrict__ out) {
  __shared__ float red[16];
  int tid = threadIdx.x;
  float s = 0.0f;
  for (int i = tid; i < 16 * Tlen; i += 1024) s += klp[i];
  s = dppSum64(s);
  int wave = tid >> 6, lane = tid & 63;
  if (lane == 63) red[wave] = s;
  __syncthreads();
  if (tid == 0) {
    float tot = 0.0f;
    #pragma unroll
    for (int w = 0; w < 16; ++w) tot += red[w];
    out[0] = accum[0];
    out[1] = 0.5f * tot;
  }
}

extern "C" void kernel_launch(void* const* d_in, const int* in_sizes, int n_in,
                              void* d_out, int out_size, void* d_ws, size_t ws_size,
                              hipStream_t stream) {
  const float* enc = (const float*)d_in[0];
  const float* W = (const float*)d_in[1];
  const float* bias = (const float*)d_in[2];
  const int* lens = (const int*)d_in[3];
  const int* targets = (const int*)d_in[4];
  const int* tlens = (const int*)d_in[5];

  char* ws = (char*)d_ws;
  u16* a_bf = (u16*)(ws + WS_ABF);
  u16* w_bf = (u16*)(ws + WS_WBF);
  u16* Zb   = (u16*)(ws + WS_Z);
  float* Gp  = (float*)(ws + WS_G);   // aliases a_bf (dead after gemm)
  float* klp = (float*)(ws + WS_KL);  // aliases w_bf (dead after gemm)
  float* accum = (float*)(ws + WS_ACC);

  hipLaunchKernelGGL(convert_kernel, dim3(1024), dim3(256), 0, stream,
                     (const float4*)enc, (const float4*)W, (uint4*)a_bf, (uint4*)w_bf,
                     lens, accum);
  hipLaunchKernelGGL(gemm_kernel, dim3(4000), dim3(256), 0, stream,
                     a_bf, w_bf, lens, Zb);
  hipLaunchKernelGGL(cr_stats_kernel, dim3(16, 1000), dim3(256), 0, stream,
                     Zb, bias, lens, targets, tlens, Gp, klp);
  hipLaunchKernelGGL(ctc_kernel, dim3(Bsz), dim3(64), 0, stream,
                     Gp, targets, lens, tlens, accum);
  hipLaunchKernelGGL(finalize_kernel, dim3(1), dim3(1024), 0, stream,
                     accum, klp, (float*)d_out);
}